// Round 2
// baseline (2523.109 us; speedup 1.0000x reference)
//
#include <hip/hip_runtime.h>
#include <hip/hip_bf16.h>
#include <cstdint>
#include <cstddef>

#define B_  8
#define S_  1024
#define D_  1024
#define H_  8
#define FF_ 4096
#define L_  2
#define DK_ 128

typedef __bf16 bf16x8 __attribute__((ext_vector_type(8)));
typedef float  f32x4  __attribute__((ext_vector_type(4)));

__device__ __forceinline__ unsigned short f2bf(float f) {
    union { float f; uint32_t u; } v; v.f = f;
    uint32_t r = v.u + 0x7fffu + ((v.u >> 16) & 1u);
    return (unsigned short)(r >> 16);
}
__device__ __forceinline__ float bf2f(unsigned short u) {
    union { uint32_t u; float f; } v; v.u = ((uint32_t)u) << 16; return v.f;
}

// ---------------------------------------------------------------- init: x = qe+pe, y = qa+pe
__global__ __launch_bounds__(256) void init_xy(
    const float* __restrict__ qe, const float* __restrict__ qa,
    const float* __restrict__ pe,
    float* __restrict__ x32, unsigned short* __restrict__ xb,
    unsigned short* __restrict__ yb)
{
    int i = (blockIdx.x * 256 + threadIdx.x) * 4;
    int pi = i & (S_ * D_ - 1);
    float4 q = *(const float4*)(qe + i);
    float4 a = *(const float4*)(qa + i);
    float4 p = *(const float4*)(pe + pi);
    float x0 = q.x + p.x, x1 = q.y + p.y, x2 = q.z + p.z, x3 = q.w + p.w;
    float y0 = a.x + p.x, y1 = a.y + p.y, y2 = a.z + p.z, y3 = a.w + p.w;
    *(float4*)(x32 + i) = make_float4(x0, x1, x2, x3);
    ushort4 xo; xo.x = f2bf(x0); xo.y = f2bf(x1); xo.z = f2bf(x2); xo.w = f2bf(x3);
    ushort4 yo; yo.x = f2bf(y0); yo.y = f2bf(y1); yo.z = f2bf(y2); yo.w = f2bf(y3);
    *(ushort4*)(xb + i) = xo;
    *(ushort4*)(yb + i) = yo;
}

// ---------------------------------------------------------------- bf16 MFMA NT-GEMM
// C[m,n] = sum_k A[m,k] * W[n,k] + bias[n]
// A: M x K bf16. W: N x K fp32, converted to bf16 during LDS staging.
// 64x64 block tile, 4 waves each 2x2 of 16x16x32 MFMA, BK=32.
template<bool RELU, bool OUTBF>
__global__ __launch_bounds__(256) void gemm_nt(
    const unsigned short* __restrict__ A, const float* __restrict__ W,
    const float* __restrict__ bias, void* __restrict__ Cout,
    int M, int N, int K)
{
    __shared__ unsigned short sA[64][40];
    __shared__ unsigned short sW[64][40];

    const int tid  = threadIdx.x;
    const int lane = tid & 63;
    const int wave = tid >> 6;
    const int m0 = blockIdx.y * 64;
    const int n0 = blockIdx.x * 64;
    const int rw = (wave >> 1) * 32;
    const int cw = (wave & 1) * 32;
    const int l16  = lane & 15;
    const int quad = lane >> 4;

    const int sr = tid >> 2;          // staging row 0..63
    const int sc = (tid & 3) * 8;     // staging col (elements)

    const unsigned short* Aptr = A + (size_t)(m0 + sr) * K + sc;
    const float*          Wptr = W + (size_t)(n0 + sr) * K + sc;

    f32x4 acc[2][2] = {};

    for (int k0 = 0; k0 < K; k0 += 32) {
        __syncthreads();
        *(uint4*)&sA[sr][sc] = *(const uint4*)(Aptr + k0);
        float4 w0 = *(const float4*)(Wptr + k0);
        float4 w1 = *(const float4*)(Wptr + k0 + 4);
        ushort4 wa; wa.x = f2bf(w0.x); wa.y = f2bf(w0.y); wa.z = f2bf(w0.z); wa.w = f2bf(w0.w);
        ushort4 wb; wb.x = f2bf(w1.x); wb.y = f2bf(w1.y); wb.z = f2bf(w1.z); wb.w = f2bf(w1.w);
        *(ushort4*)&sW[sr][sc]     = wa;
        *(ushort4*)&sW[sr][sc + 4] = wb;
        __syncthreads();
        bf16x8 af0 = *(const bf16x8*)&sA[rw      + l16][quad * 8];
        bf16x8 af1 = *(const bf16x8*)&sA[rw + 16 + l16][quad * 8];
        bf16x8 bw0 = *(const bf16x8*)&sW[cw      + l16][quad * 8];
        bf16x8 bw1 = *(const bf16x8*)&sW[cw + 16 + l16][quad * 8];
        acc[0][0] = __builtin_amdgcn_mfma_f32_16x16x32_bf16(af0, bw0, acc[0][0], 0, 0, 0);
        acc[0][1] = __builtin_amdgcn_mfma_f32_16x16x32_bf16(af0, bw1, acc[0][1], 0, 0, 0);
        acc[1][0] = __builtin_amdgcn_mfma_f32_16x16x32_bf16(af1, bw0, acc[1][0], 0, 0, 0);
        acc[1][1] = __builtin_amdgcn_mfma_f32_16x16x32_bf16(af1, bw1, acc[1][1], 0, 0, 0);
    }

    // C/D layout: col=lane&15, row=(lane>>4)*4+reg  [verified m89/m91]
    #pragma unroll
    for (int i = 0; i < 2; ++i)
        #pragma unroll
        for (int j = 0; j < 2; ++j) {
            int row = m0 + rw + i * 16 + quad * 4;
            int col = n0 + cw + j * 16 + l16;
            float bcol = bias[col];
            #pragma unroll
            for (int r = 0; r < 4; ++r) {
                float v = acc[i][j][r] + bcol;
                if (RELU) v = fmaxf(v, 0.0f);
                if (OUTBF)
                    ((unsigned short*)Cout)[(size_t)(row + r) * N + col] = f2bf(v);
                else
                    ((float*)Cout)[(size_t)(row + r) * N + col] = v;
            }
        }
}

// ---------------------------------------------------------------- attention
// Q == K (kq_same), bf16 K/V, fp32 compute. Strict causal (j < q). Row 0 out = 0.
// One block per (b, h, 8-query tile). Scores tile in LDS (8 x 1024 fp32).
__global__ __launch_bounds__(256) void attn_kernel(
    const unsigned short* __restrict__ Kbuf, const unsigned short* __restrict__ Vbuf,
    unsigned short* __restrict__ Obuf)
{
    __shared__ float sQ[8][128];
    __shared__ float sS[8][1024];
    __shared__ float red[8][32];
    __shared__ float rowm[8], rowinv[8];

    const int tid = threadIdx.x;
    const int q0  = blockIdx.x * 8;
    const int bh  = blockIdx.y;
    const int b   = bh >> 3, h = bh & 7;
    const unsigned short* Kb = Kbuf + ((size_t)b * S_) * D_ + h * DK_;
    const unsigned short* Vb = Vbuf + ((size_t)b * S_) * D_ + h * DK_;

    // load Q tile (= K rows q0..q0+7): 8 rows x 16 uint4 (8 bf16 each)
    for (int idx = tid; idx < 8 * 16; idx += 256) {
        int r = idx >> 4, c8 = (idx & 15) * 8;
        uint4 u = *(const uint4*)(Kb + (size_t)(q0 + r) * D_ + c8);
        const unsigned short* us = (const unsigned short*)&u;
        #pragma unroll
        for (int t = 0; t < 8; ++t) sQ[r][c8 + t] = bf2f(us[t]);
    }
    __syncthreads();

    const int jend = q0 + 8;

    // phase 1: scores
    const float scale = 0.08838834764831845f;   // 1/sqrt(128)
    for (int j = tid; j < jend; j += 256) {
        const unsigned short* Kr = Kb + (size_t)j * D_;
        float acc[8] = {};
        #pragma unroll 2
        for (int d8 = 0; d8 < 16; ++d8) {
            uint4 u = *(const uint4*)(Kr + d8 * 8);
            const unsigned short* us = (const unsigned short*)&u;
            float kf[8];
            #pragma unroll
            for (int t = 0; t < 8; ++t) kf[t] = bf2f(us[t]);
            #pragma unroll
            for (int r = 0; r < 8; ++r) {
                float s = 0.0f;
                #pragma unroll
                for (int t = 0; t < 8; ++t) s += kf[t] * sQ[r][d8 * 8 + t];
                acc[r] += s;
            }
        }
        #pragma unroll
        for (int r = 0; r < 8; ++r) sS[r][j] = acc[r] * scale;
    }
    __syncthreads();

    // softmax over j < q (strict causal); masked entries -> 0
    {
        const int r = tid >> 5;
        const int sub = tid & 31;
        const int q = q0 + r;
        float lm = -1e30f;
        for (int j = sub; j < q; j += 32) lm = fmaxf(lm, sS[r][j]);
        red[r][sub] = lm;
        __syncthreads();
        if (sub == 0) {
            float m = -1e30f;
            for (int t = 0; t < 32; ++t) m = fmaxf(m, red[r][t]);
            rowm[r] = m;
        }
        __syncthreads();
        float m = rowm[r];
        float ls = 0.0f;
        for (int j = sub; j < q; j += 32) {
            float e = __expf(sS[r][j] - m);
            sS[r][j] = e;
            ls += e;
        }
        for (int j = q + sub; j < jend; j += 32) sS[r][j] = 0.0f;
        red[r][sub] = ls;
        __syncthreads();
        if (sub == 0) {
            float s = 0.0f;
            for (int t = 0; t < 32; ++t) s += red[r][t];
            rowinv[r] = (s > 0.0f) ? 1.0f / s : 0.0f;   // q==0 row -> 0 (zero_pad)
        }
        __syncthreads();
    }

    // phase 2: O[r][d] = inv[r] * sum_j p[r][j] * V[j][d]
    {
        const int d = tid & 127;
        const int g = tid >> 7;
        float acc[4] = {};
        for (int j = 0; j < jend; ++j) {
            float v = bf2f(Vb[(size_t)j * D_ + d]);
            #pragma unroll
            for (int rr = 0; rr < 4; ++rr)
                acc[rr] += sS[g * 4 + rr][j] * v;
        }
        #pragma unroll
        for (int rr = 0; rr < 4; ++rr) {
            int row = g * 4 + rr;
            float o = acc[rr] * rowinv[row];
            Obuf[((size_t)b * S_ + q0 + row) * D_ + h * DK_ + d] = f2bf(o);
        }
    }
}

// ---------------------------------------------------------------- residual + LayerNorm
// t = x + delta(bf16); out = LN(t)*g + b ; writes fp32 out and bf16 copy
__global__ __launch_bounds__(256) void ln_res(
    const float* __restrict__ xin, const unsigned short* __restrict__ delta,
    const float* __restrict__ g, const float* __restrict__ bta,
    float* __restrict__ xout, unsigned short* __restrict__ xbout)
{
    __shared__ float red1[4], red2[4];
    const int row = blockIdx.x;
    const int tid = threadIdx.x;
    const int c = tid * 4;
    const float* xr = xin + (size_t)row * D_;
    const unsigned short* dr = delta + (size_t)row * D_;
    float4 xv = *(const float4*)(xr + c);
    ushort4 du = *(const ushort4*)(dr + c);
    float t0 = xv.x + bf2f(du.x), t1 = xv.y + bf2f(du.y);
    float t2 = xv.z + bf2f(du.z), t3 = xv.w + bf2f(du.w);

    float s = t0 + t1 + t2 + t3;
    #pragma unroll
    for (int off = 32; off > 0; off >>= 1) s += __shfl_down(s, off);
    if ((tid & 63) == 0) red1[tid >> 6] = s;
    __syncthreads();
    float mean = (red1[0] + red1[1] + red1[2] + red1[3]) * (1.0f / 1024.0f);

    float e0 = t0 - mean, e1 = t1 - mean, e2 = t2 - mean, e3 = t3 - mean;
    float ss = e0 * e0 + e1 * e1 + e2 * e2 + e3 * e3;
    #pragma unroll
    for (int off = 32; off > 0; off >>= 1) ss += __shfl_down(ss, off);
    if ((tid & 63) == 0) red2[tid >> 6] = ss;
    __syncthreads();
    float var = (red2[0] + red2[1] + red2[2] + red2[3]) * (1.0f / 1024.0f);
    float rstd = rsqrtf(var + 1e-5f);

    float4 gv = *(const float4*)(g + c);
    float4 bv = *(const float4*)(bta + c);
    float o0 = e0 * rstd * gv.x + bv.x;
    float o1 = e1 * rstd * gv.y + bv.y;
    float o2 = e2 * rstd * gv.z + bv.z;
    float o3 = e3 * rstd * gv.w + bv.w;
    *(float4*)(xout + (size_t)row * D_ + c) = make_float4(o0, o1, o2, o3);
    ushort4 ob; ob.x = f2bf(o0); ob.y = f2bf(o1); ob.z = f2bf(o2); ob.w = f2bf(o3);
    *(ushort4*)(xbout + (size_t)row * D_ + c) = ob;
}

// ---------------------------------------------------------------- driver
extern "C" void kernel_launch(void* const* d_in, const int* in_sizes, int n_in,
                              void* d_out, int out_size, void* d_ws, size_t ws_size,
                              hipStream_t stream)
{
    const float* qe   = (const float*)d_in[0];
    const float* qa   = (const float*)d_in[1];
    const float* pe   = (const float*)d_in[2];
    const float* Wk   = (const float*)d_in[3];
    const float* bk   = (const float*)d_in[4];
    const float* Wv   = (const float*)d_in[5];
    const float* bv   = (const float*)d_in[6];
    const float* Wo   = (const float*)d_in[7];
    const float* bo   = (const float*)d_in[8];
    const float* ln1g = (const float*)d_in[9];
    const float* ln1b = (const float*)d_in[10];
    const float* W1   = (const float*)d_in[11];
    const float* b1   = (const float*)d_in[12];
    const float* W2   = (const float*)d_in[13];
    const float* b2   = (const float*)d_in[14];
    const float* ln2g = (const float*)d_in[15];
    const float* ln2b = (const float*)d_in[16];

    const size_t BSD = (size_t)B_ * S_ * D_;   // 8388608
    const size_t BSF = (size_t)B_ * S_ * FF_;  // 33554432

    // workspace layout (~151 MB):
    //   x32   fp32  33.55 MB   persistent residual
    //   xb    bf16  16.78 MB
    //   yb    bf16  16.78 MB
    //   delta bf16  16.78 MB
    //   union       67.11 MB   {Kb,Vb,attnb} (50.3) | hb (67.1) - lifetimes disjoint
    char* p = (char*)d_ws;
    auto take = [&](size_t bytes) { char* r = p; p += (bytes + 255) & ~255ULL; return r; };
    float*          x32   = (float*)take(BSD * 4);
    unsigned short* xb    = (unsigned short*)take(BSD * 2);
    unsigned short* yb    = (unsigned short*)take(BSD * 2);
    unsigned short* delta = (unsigned short*)take(BSD * 2);
    char*           uni   = take(BSF * 2);
    unsigned short* Kb    = (unsigned short*)uni;
    unsigned short* Vb    = Kb + BSD;
    unsigned short* attnb = Vb + BSD;
    unsigned short* hb    = (unsigned short*)uni;

    init_xy<<<(int)(BSD / 4 / 256), 256, 0, stream>>>(qe, qa, pe, x32, xb, yb);

    const int M = B_ * S_;  // 8192
    for (int l = 0; l < L_; ++l) {
        gemm_nt<false, true><<<dim3(D_ / 64, M / 64), 256, 0, stream>>>(
            xb, Wk + (size_t)l * D_ * D_, bk + l * D_, Kb, M, D_, D_);
        gemm_nt<false, true><<<dim3(D_ / 64, M / 64), 256, 0, stream>>>(
            yb, Wv + (size_t)l * D_ * D_, bv + l * D_, Vb, M, D_, D_);
        attn_kernel<<<dim3(S_ / 8, B_ * H_), 256, 0, stream>>>(Kb, Vb, attnb);
        gemm_nt<false, true><<<dim3(D_ / 64, M / 64), 256, 0, stream>>>(
            attnb, Wo + (size_t)l * D_ * D_, bo + l * D_, delta, M, D_, D_);
        ln_res<<<M, 256, 0, stream>>>(x32, delta, ln1g + l * D_, ln1b + l * D_, x32, xb);
        gemm_nt<true, true><<<dim3(FF_ / 64, M / 64), 256, 0, stream>>>(
            xb, W1 + (size_t)l * FF_ * D_, b1 + l * FF_, hb, M, FF_, D_);
        gemm_nt<false, true><<<dim3(D_ / 64, M / 64), 256, 0, stream>>>(
            hb, W2 + (size_t)l * D_ * FF_, b2 + l * D_, delta, M, D_, FF_);
        float* xo = (l == L_ - 1) ? (float*)d_out : x32;
        ln_res<<<M, 256, 0, stream>>>(x32, delta, ln2g + l * D_, ln2b + l * D_, xo, xb);
    }
}

// Round 3
// 1514.044 us; speedup vs baseline: 1.6665x; 1.6665x over previous
//
#include <hip/hip_runtime.h>
#include <hip/hip_bf16.h>
#include <cstdint>
#include <cstddef>

#define B_  8
#define S_  1024
#define D_  1024
#define H_  8
#define FF_ 4096
#define L_  2
#define DK_ 128

typedef __bf16 bf16x8 __attribute__((ext_vector_type(8)));
typedef float  f32x4  __attribute__((ext_vector_type(4)));

__device__ __forceinline__ unsigned short f2bf(float f) {
    union { float f; uint32_t u; } v; v.f = f;
    uint32_t r = v.u + 0x7fffu + ((v.u >> 16) & 1u);
    return (unsigned short)(r >> 16);
}
__device__ __forceinline__ float bf2f(unsigned short u) {
    union { uint32_t u; float f; } v; v.u = ((uint32_t)u) << 16; return v.f;
}

// ---------------------------------------------------------------- init: x = qe+pe, y = qa+pe
__global__ __launch_bounds__(256) void init_xy(
    const float* __restrict__ qe, const float* __restrict__ qa,
    const float* __restrict__ pe,
    float* __restrict__ x32, unsigned short* __restrict__ xb,
    unsigned short* __restrict__ yb)
{
    int i = (blockIdx.x * 256 + threadIdx.x) * 4;
    int pi = i & (S_ * D_ - 1);
    float4 q = *(const float4*)(qe + i);
    float4 a = *(const float4*)(qa + i);
    float4 p = *(const float4*)(pe + pi);
    float x0 = q.x + p.x, x1 = q.y + p.y, x2 = q.z + p.z, x3 = q.w + p.w;
    float y0 = a.x + p.x, y1 = a.y + p.y, y2 = a.z + p.z, y3 = a.w + p.w;
    *(float4*)(x32 + i) = make_float4(x0, x1, x2, x3);
    ushort4 xo; xo.x = f2bf(x0); xo.y = f2bf(x1); xo.z = f2bf(x2); xo.w = f2bf(x3);
    ushort4 yo; yo.x = f2bf(y0); yo.y = f2bf(y1); yo.z = f2bf(y2); yo.w = f2bf(y3);
    *(ushort4*)(xb + i) = xo;
    *(ushort4*)(yb + i) = yo;
}

// ---------------------------------------------------------------- bf16 MFMA NT-GEMM
// C[m,n] = sum_k A[m,k] * W[n,k] + bias[n]
// A: M x K bf16. W: N x K fp32, converted to bf16 during LDS staging.
// OMODE: 1 = bf16 row-major out; 2 = bf16 per-head-transposed out [b,h][dim][key]
template<bool RELU, int OMODE>
__global__ __launch_bounds__(256) void gemm_nt(
    const unsigned short* __restrict__ A, const float* __restrict__ W,
    const float* __restrict__ bias, void* __restrict__ Cout,
    int M, int N, int K)
{
    __shared__ unsigned short sA[64][40];
    __shared__ unsigned short sW[64][40];

    const int tid  = threadIdx.x;
    const int lane = tid & 63;
    const int wave = tid >> 6;
    const int m0 = blockIdx.y * 64;
    const int n0 = blockIdx.x * 64;
    const int rw = (wave >> 1) * 32;
    const int cw = (wave & 1) * 32;
    const int l16  = lane & 15;
    const int quad = lane >> 4;

    const int sr = tid >> 2;
    const int sc = (tid & 3) * 8;

    const unsigned short* Aptr = A + (size_t)(m0 + sr) * K + sc;
    const float*          Wptr = W + (size_t)(n0 + sr) * K + sc;

    f32x4 acc[2][2] = {};

    for (int k0 = 0; k0 < K; k0 += 32) {
        __syncthreads();
        *(uint4*)&sA[sr][sc] = *(const uint4*)(Aptr + k0);
        float4 w0 = *(const float4*)(Wptr + k0);
        float4 w1 = *(const float4*)(Wptr + k0 + 4);
        ushort4 wa; wa.x = f2bf(w0.x); wa.y = f2bf(w0.y); wa.z = f2bf(w0.z); wa.w = f2bf(w0.w);
        ushort4 wb; wb.x = f2bf(w1.x); wb.y = f2bf(w1.y); wb.z = f2bf(w1.z); wb.w = f2bf(w1.w);
        *(ushort4*)&sW[sr][sc]     = wa;
        *(ushort4*)&sW[sr][sc + 4] = wb;
        __syncthreads();
        bf16x8 af0 = *(const bf16x8*)&sA[rw      + l16][quad * 8];
        bf16x8 af1 = *(const bf16x8*)&sA[rw + 16 + l16][quad * 8];
        bf16x8 bw0 = *(const bf16x8*)&sW[cw      + l16][quad * 8];
        bf16x8 bw1 = *(const bf16x8*)&sW[cw + 16 + l16][quad * 8];
        acc[0][0] = __builtin_amdgcn_mfma_f32_16x16x32_bf16(af0, bw0, acc[0][0], 0, 0, 0);
        acc[0][1] = __builtin_amdgcn_mfma_f32_16x16x32_bf16(af0, bw1, acc[0][1], 0, 0, 0);
        acc[1][0] = __builtin_amdgcn_mfma_f32_16x16x32_bf16(af1, bw0, acc[1][0], 0, 0, 0);
        acc[1][1] = __builtin_amdgcn_mfma_f32_16x16x32_bf16(af1, bw1, acc[1][1], 0, 0, 0);
    }

    // C/D layout: col=lane&15, row=(lane>>4)*4+reg
    #pragma unroll
    for (int i = 0; i < 2; ++i)
        #pragma unroll
        for (int j = 0; j < 2; ++j) {
            int row = m0 + rw + i * 16 + quad * 4;   // base of 4 consecutive rows
            int col = n0 + cw + j * 16 + l16;
            float bcol = bias[col];
            float v[4];
            #pragma unroll
            for (int r = 0; r < 4; ++r) {
                v[r] = acc[i][j][r] + bcol;
                if (RELU) v[r] = fmaxf(v[r], 0.0f);
            }
            if (OMODE == 1) {
                #pragma unroll
                for (int r = 0; r < 4; ++r)
                    ((unsigned short*)Cout)[(size_t)(row + r) * N + col] = f2bf(v[r]);
            } else {   // OMODE == 2: [b,h][dim][key], rows are consecutive keys
                int key = row & (S_ - 1);
                int bb  = row >> 10;
                int hh  = col >> 7, dim = col & (DK_ - 1);
                unsigned short* dst = (unsigned short*)Cout
                    + ((size_t)(bb * H_ + hh) * DK_ + dim) * S_ + key;
                ushort4 o4; o4.x = f2bf(v[0]); o4.y = f2bf(v[1]);
                o4.z = f2bf(v[2]); o4.w = f2bf(v[3]);
                *(ushort4*)dst = o4;
            }
        }
}

// ---------------------------------------------------------------- MFMA flash attention
// Q == K (kq_same). Strict causal (j < q). Row 0 output = 0 (zero_pad).
// K: [b][key][h*128+dim] bf16 row-major. Vt: [b,h][dim][key] bf16.
// Block = 64 q-rows (4 waves x 16 rows), iterates 64-key tiles with online softmax.
__global__ __launch_bounds__(256) void attn_mfma(
    const unsigned short* __restrict__ Kbuf, const unsigned short* __restrict__ Vtbuf,
    unsigned short* __restrict__ Obuf)
{
    __shared__ unsigned short sK[64][136];        // keys x dk, stride 272B (16B-aligned)
    __shared__ unsigned short sVt[128][72];       // dim x keys, stride 144B
    __shared__ unsigned short sP[4][16][72];      // per-wave P tile, A-layout rows

    const int tid  = threadIdx.x;
    const int lane = tid & 63;
    const int w    = tid >> 6;
    const int l16  = lane & 15;
    const int quad = lane >> 4;
    const int qt   = (S_ / 64 - 1) - blockIdx.x;  // heavy tiles first
    const int q0   = qt * 64;
    const int bh   = blockIdx.y;
    const int b    = bh >> 3, h = bh & 7;
    const unsigned short* KB  = Kbuf  + ((size_t)b * S_) * D_ + h * DK_;
    const unsigned short* VTB = Vtbuf + (size_t)bh * DK_ * S_;

    // Q fragments (A-layout: row m = lane&15, k = quad*8+j), kept in registers
    bf16x8 qf[4];
    {
        const unsigned short* qrow = KB + (size_t)(q0 + w * 16 + l16) * D_ + quad * 8;
        #pragma unroll
        for (int ks = 0; ks < 4; ++ks)
            qf[ks] = *(const bf16x8*)(qrow + ks * 32);
    }

    f32x4 Oacc[8] = {};
    float m_run[4] = {-1e30f, -1e30f, -1e30f, -1e30f};
    float l_run[4] = {};
    const float scale = 0.08838834764831845f;     // 1/sqrt(128)

    for (int kt = 0; kt <= qt; ++kt) {
        __syncthreads();
        // stage K tile (64 keys x 128 dk) row-major, coalesced
        #pragma unroll
        for (int i = 0; i < 4; ++i) {
            int idx = tid + i * 256;
            int r = idx >> 4, c8 = (idx & 15) * 8;
            *(uint4*)&sK[r][c8] = *(const uint4*)(KB + (size_t)(kt * 64 + r) * D_ + c8);
        }
        // stage V^T tile (128 dim x 64 keys) from pre-transposed global, coalesced
        #pragma unroll
        for (int i = 0; i < 4; ++i) {
            int idx = tid + i * 256;
            int dim = idx >> 3, k8 = (idx & 7) * 8;
            *(uint4*)&sVt[dim][k8] = *(const uint4*)(VTB + (size_t)dim * S_ + kt * 64 + k8);
        }
        __syncthreads();

        // S = Q K^T  (wave computes its 16 rows x 64 keys)
        f32x4 sacc[4];
        #pragma unroll
        for (int nt = 0; nt < 4; ++nt) {
            f32x4 a = {};
            #pragma unroll
            for (int ks = 0; ks < 4; ++ks) {
                bf16x8 kf = *(const bf16x8*)&sK[nt * 16 + l16][ks * 32 + quad * 8];
                a = __builtin_amdgcn_mfma_f32_16x16x32_bf16(qf[ks], kf, a, 0, 0, 0);
            }
            sacc[nt] = a;
        }

        // scale + strict-causal mask on diagonal tile
        const bool diag = (kt == qt);
        #pragma unroll
        for (int nt = 0; nt < 4; ++nt)
            #pragma unroll
            for (int r = 0; r < 4; ++r) {
                float v = sacc[nt][r] * scale;
                if (diag) {
                    int nidx = nt * 16 + l16;
                    int midx = w * 16 + quad * 4 + r;
                    if (nidx >= midx) v = -1e30f;
                }
                sacc[nt][r] = v;
            }

        // online softmax update (rows = quad*4+r, cols across 16 lanes of quad)
        float alpha[4];
        #pragma unroll
        for (int r = 0; r < 4; ++r) {
            float mx = fmaxf(fmaxf(sacc[0][r], sacc[1][r]), fmaxf(sacc[2][r], sacc[3][r]));
            mx = fmaxf(mx, __shfl_xor(mx, 1));
            mx = fmaxf(mx, __shfl_xor(mx, 2));
            mx = fmaxf(mx, __shfl_xor(mx, 4));
            mx = fmaxf(mx, __shfl_xor(mx, 8));
            float mn = fmaxf(m_run[r], mx);
            alpha[r] = __expf(m_run[r] - mn);
            m_run[r] = mn;
        }
        #pragma unroll
        for (int r = 0; r < 4; ++r) {
            float rs = 0.0f;
            #pragma unroll
            for (int nt = 0; nt < 4; ++nt) {
                float e = __expf(sacc[nt][r] - m_run[r]);
                sacc[nt][r] = e;
                rs += e;
            }
            rs += __shfl_xor(rs, 1);
            rs += __shfl_xor(rs, 2);
            rs += __shfl_xor(rs, 4);
            rs += __shfl_xor(rs, 8);
            l_run[r] = l_run[r] * alpha[r] + rs;
        }
        #pragma unroll
        for (int o = 0; o < 8; ++o)
            #pragma unroll
            for (int r = 0; r < 4; ++r)
                Oacc[o][r] *= alpha[r];

        // P (C/D layout) -> LDS (A-layout rows), wave-private region
        #pragma unroll
        for (int nt = 0; nt < 4; ++nt)
            #pragma unroll
            for (int r = 0; r < 4; ++r)
                sP[w][quad * 4 + r][nt * 16 + l16] = f2bf(sacc[nt][r]);

        // O += P @ V  (Vt as NT operand: O[m][n] = sum_k P[m,k] Vt[n,k])
        bf16x8 pf[2];
        #pragma unroll
        for (int ks = 0; ks < 2; ++ks)
            pf[ks] = *(const bf16x8*)&sP[w][l16][ks * 32 + quad * 8];
        #pragma unroll
        for (int nt = 0; nt < 8; ++nt) {
            #pragma unroll
            for (int ks = 0; ks < 2; ++ks) {
                bf16x8 vf = *(const bf16x8*)&sVt[nt * 16 + l16][ks * 32 + quad * 8];
                Oacc[nt] = __builtin_amdgcn_mfma_f32_16x16x32_bf16(pf[ks], vf, Oacc[nt], 0, 0, 0);
            }
        }
    }

    // finalize: O *= 1/l  (0 for empty rows and the zero_pad row q==0)
    float inv[4];
    #pragma unroll
    for (int r = 0; r < 4; ++r) {
        int m = q0 + w * 16 + quad * 4 + r;
        inv[r] = (l_run[r] > 0.0f && m != 0) ? 1.0f / l_run[r] : 0.0f;
    }
    #pragma unroll
    for (int nt = 0; nt < 8; ++nt)
        #pragma unroll
        for (int r = 0; r < 4; ++r) {
            int m = q0 + w * 16 + quad * 4 + r;
            Obuf[((size_t)b * S_ + m) * D_ + h * DK_ + nt * 16 + l16] =
                f2bf(Oacc[nt][r] * inv[r]);
        }
}

// ---------------------------------------------------------------- residual + LayerNorm
__global__ __launch_bounds__(256) void ln_res(
    const float* __restrict__ xin, const unsigned short* __restrict__ delta,
    const float* __restrict__ g, const float* __restrict__ bta,
    float* __restrict__ xout, unsigned short* __restrict__ xbout)
{
    __shared__ float red1[4], red2[4];
    const int row = blockIdx.x;
    const int tid = threadIdx.x;
    const int c = tid * 4;
    const float* xr = xin + (size_t)row * D_;
    const unsigned short* dr = delta + (size_t)row * D_;
    float4 xv = *(const float4*)(xr + c);
    ushort4 du = *(const ushort4*)(dr + c);
    float t0 = xv.x + bf2f(du.x), t1 = xv.y + bf2f(du.y);
    float t2 = xv.z + bf2f(du.z), t3 = xv.w + bf2f(du.w);

    float s = t0 + t1 + t2 + t3;
    #pragma unroll
    for (int off = 32; off > 0; off >>= 1) s += __shfl_down(s, off);
    if ((tid & 63) == 0) red1[tid >> 6] = s;
    __syncthreads();
    float mean = (red1[0] + red1[1] + red1[2] + red1[3]) * (1.0f / 1024.0f);

    float e0 = t0 - mean, e1 = t1 - mean, e2 = t2 - mean, e3 = t3 - mean;
    float ss = e0 * e0 + e1 * e1 + e2 * e2 + e3 * e3;
    #pragma unroll
    for (int off = 32; off > 0; off >>= 1) ss += __shfl_down(ss, off);
    if ((tid & 63) == 0) red2[tid >> 6] = ss;
    __syncthreads();
    float var = (red2[0] + red2[1] + red2[2] + red2[3]) * (1.0f / 1024.0f);
    float rstd = rsqrtf(var + 1e-5f);

    float4 gv = *(const float4*)(g + c);
    float4 bv = *(const float4*)(bta + c);
    float o0 = e0 * rstd * gv.x + bv.x;
    float o1 = e1 * rstd * gv.y + bv.y;
    float o2 = e2 * rstd * gv.z + bv.z;
    float o3 = e3 * rstd * gv.w + bv.w;
    *(float4*)(xout + (size_t)row * D_ + c) = make_float4(o0, o1, o2, o3);
    ushort4 ob; ob.x = f2bf(o0); ob.y = f2bf(o1); ob.z = f2bf(o2); ob.w = f2bf(o3);
    *(ushort4*)(xbout + (size_t)row * D_ + c) = ob;
}

// ---------------------------------------------------------------- driver
extern "C" void kernel_launch(void* const* d_in, const int* in_sizes, int n_in,
                              void* d_out, int out_size, void* d_ws, size_t ws_size,
                              hipStream_t stream)
{
    const float* qe   = (const float*)d_in[0];
    const float* qa   = (const float*)d_in[1];
    const float* pe   = (const float*)d_in[2];
    const float* Wk   = (const float*)d_in[3];
    const float* bk   = (const float*)d_in[4];
    const float* Wv   = (const float*)d_in[5];
    const float* bv   = (const float*)d_in[6];
    const float* Wo   = (const float*)d_in[7];
    const float* bo   = (const float*)d_in[8];
    const float* ln1g = (const float*)d_in[9];
    const float* ln1b = (const float*)d_in[10];
    const float* W1   = (const float*)d_in[11];
    const float* b1   = (const float*)d_in[12];
    const float* W2   = (const float*)d_in[13];
    const float* b2   = (const float*)d_in[14];
    const float* ln2g = (const float*)d_in[15];
    const float* ln2b = (const float*)d_in[16];

    const size_t BSD = (size_t)B_ * S_ * D_;
    const size_t BSF = (size_t)B_ * S_ * FF_;

    char* p = (char*)d_ws;
    auto take = [&](size_t bytes) { char* r = p; p += (bytes + 255) & ~255ULL; return r; };
    float*          x32   = (float*)take(BSD * 4);
    unsigned short* xb    = (unsigned short*)take(BSD * 2);
    unsigned short* yb    = (unsigned short*)take(BSD * 2);
    unsigned short* delta = (unsigned short*)take(BSD * 2);
    char*           uni   = take(BSF * 2);
    unsigned short* Kb    = (unsigned short*)uni;
    unsigned short* Vt    = Kb + BSD;      // [b,h][dim][key]
    unsigned short* attnb = Vt + BSD;
    unsigned short* hb    = (unsigned short*)uni;

    init_xy<<<(int)(BSD / 4 / 256), 256, 0, stream>>>(qe, qa, pe, x32, xb, yb);

    const int M = B_ * S_;
    for (int l = 0; l < L_; ++l) {
        gemm_nt<false, 1><<<dim3(D_ / 64, M / 64), 256, 0, stream>>>(
            xb, Wk + (size_t)l * D_ * D_, bk + l * D_, Kb, M, D_, D_);
        gemm_nt<false, 2><<<dim3(D_ / 64, M / 64), 256, 0, stream>>>(
            yb, Wv + (size_t)l * D_ * D_, bv + l * D_, Vt, M, D_, D_);
        attn_mfma<<<dim3(S_ / 64, B_ * H_), 256, 0, stream>>>(Kb, Vt, attnb);
        gemm_nt<false, 1><<<dim3(D_ / 64, M / 64), 256, 0, stream>>>(
            attnb, Wo + (size_t)l * D_ * D_, bo + l * D_, delta, M, D_, D_);
        ln_res<<<M, 256, 0, stream>>>(x32, delta, ln1g + l * D_, ln1b + l * D_, x32, xb);
        gemm_nt<true, 1><<<dim3(FF_ / 64, M / 64), 256, 0, stream>>>(
            xb, W1 + (size_t)l * FF_ * D_, b1 + l * FF_, hb, M, FF_, D_);
        gemm_nt<false, 1><<<dim3(D_ / 64, M / 64), 256, 0, stream>>>(
            hb, W2 + (size_t)l * D_ * FF_, b2 + l * D_, delta, M, D_, FF_);
        float* xo = (l == L_ - 1) ? (float*)d_out : x32;
        ln_res<<<M, 256, 0, stream>>>(x32, delta, ln2g + l * D_, ln2b + l * D_, xo, xb);
    }
}

// Round 4
// 1081.373 us; speedup vs baseline: 2.3332x; 1.4001x over previous
//
#include <hip/hip_runtime.h>
#include <hip/hip_bf16.h>
#include <cstdint>
#include <cstddef>

#define B_  8
#define S_  1024
#define D_  1024
#define H_  8
#define FF_ 4096
#define L_  2
#define DK_ 128

typedef __bf16 bf16x8 __attribute__((ext_vector_type(8)));
typedef float  f32x4  __attribute__((ext_vector_type(4)));

__device__ __forceinline__ unsigned short f2bf(float f) {
    union { float f; uint32_t u; } v; v.f = f;
    uint32_t r = v.u + 0x7fffu + ((v.u >> 16) & 1u);
    return (unsigned short)(r >> 16);
}
__device__ __forceinline__ float bf2f(unsigned short u) {
    union { uint32_t u; float f; } v; v.u = ((uint32_t)u) << 16; return v.f;
}

// ---------------------------------------------------------------- init: x = qe+pe, y = qa+pe
__global__ __launch_bounds__(256) void init_xy(
    const float* __restrict__ qe, const float* __restrict__ qa,
    const float* __restrict__ pe,
    float* __restrict__ x32, unsigned short* __restrict__ xb,
    unsigned short* __restrict__ yb)
{
    int i = (blockIdx.x * 256 + threadIdx.x) * 4;
    int pi = i & (S_ * D_ - 1);
    float4 q = *(const float4*)(qe + i);
    float4 a = *(const float4*)(qa + i);
    float4 p = *(const float4*)(pe + pi);
    float x0 = q.x + p.x, x1 = q.y + p.y, x2 = q.z + p.z, x3 = q.w + p.w;
    float y0 = a.x + p.x, y1 = a.y + p.y, y2 = a.z + p.z, y3 = a.w + p.w;
    *(float4*)(x32 + i) = make_float4(x0, x1, x2, x3);
    ushort4 xo; xo.x = f2bf(x0); xo.y = f2bf(x1); xo.z = f2bf(x2); xo.w = f2bf(x3);
    ushort4 yo; yo.x = f2bf(y0); yo.y = f2bf(y1); yo.z = f2bf(y2); yo.w = f2bf(y3);
    *(ushort4*)(xb + i) = xo;
    *(ushort4*)(yb + i) = yo;
}

// ---------------------------------------------------------------- fp32 -> bf16 weight convert
__global__ __launch_bounds__(256) void cvt_bf16(
    const float* __restrict__ in, unsigned short* __restrict__ out)
{
    int i = (blockIdx.x * 256 + threadIdx.x) * 4;
    float4 f = *(const float4*)(in + i);
    ushort4 o; o.x = f2bf(f.x); o.y = f2bf(f.y); o.z = f2bf(f.z); o.w = f2bf(f.w);
    *(ushort4*)(out + i) = o;
}

// ---------------------------------------------------------------- m97-style bf16 MFMA NT-GEMM
// C[m,n] = sum_k A[m,k] * W[n,k] + bias[n]   (A: MxK bf16, W: NxK bf16)
// 128x128 tile, BK=64, 4 waves (2x2) each computing 4x4 of 16x16x32 MFMA.
// global_load_lds width=16 staging; XOR-chunk swizzle (chunk^row&7) kills bank conflicts.
// OMODE: 1 = bf16 row-major out; 2 = bf16 per-head-transposed out [b,h][dim][key]
template<bool RELU, int OMODE>
__global__ __launch_bounds__(256) void gemm_bt(
    const unsigned short* __restrict__ A, const unsigned short* __restrict__ W,
    const float* __restrict__ bias, void* __restrict__ Cout,
    int M, int N, int K)
{
    __shared__ unsigned short sA[128][64];   // unpadded: global_load_lds needs lane-contiguous
    __shared__ unsigned short sW[128][64];

    const int tid  = threadIdx.x;
    const int lane = tid & 63;
    const int w    = tid >> 6;
    const int l16  = lane & 15;
    const int quad = lane >> 4;
    const int m0 = blockIdx.y * 128;
    const int n0 = blockIdx.x * 128;
    const int rw = (w >> 1) * 64;
    const int cw = (w & 1) * 64;

    const int srow   = lane >> 3;            // 0..7 within the 8-row group per inst
    const int schunk = lane & 7;             // 16B chunk within a 128B row slice

    f32x4 acc[4][4] = {};

    for (int k0 = 0; k0 < K; k0 += 64) {
        __syncthreads();
        #pragma unroll
        for (int i = 0; i < 4; ++i) {
            int r0  = w * 32 + i * 8;        // wave-uniform LDS row base
            int row = r0 + srow;
            int gc  = schunk ^ (row & 7);    // source-side swizzle
            const unsigned short* ga = A + (size_t)(m0 + row) * K + k0 + gc * 8;
            const unsigned short* gw = W + (size_t)(n0 + row) * K + k0 + gc * 8;
            __builtin_amdgcn_global_load_lds(
                (const __attribute__((address_space(1))) unsigned int*)ga,
                (__attribute__((address_space(3))) unsigned int*)&sA[r0][0], 16, 0, 0);
            __builtin_amdgcn_global_load_lds(
                (const __attribute__((address_space(1))) unsigned int*)gw,
                (__attribute__((address_space(3))) unsigned int*)&sW[r0][0], 16, 0, 0);
        }
        __syncthreads();

        #pragma unroll
        for (int ks = 0; ks < 2; ++ks) {
            bf16x8 af[4], wf[4];
            #pragma unroll
            for (int t = 0; t < 4; ++t) {
                int arow = rw + t * 16 + l16;
                int achk = (ks * 4 + quad) ^ (arow & 7);
                af[t] = *(const bf16x8*)&sA[arow][achk * 8];
                int wrow = cw + t * 16 + l16;
                int wchk = (ks * 4 + quad) ^ (wrow & 7);
                wf[t] = *(const bf16x8*)&sW[wrow][wchk * 8];
            }
            #pragma unroll
            for (int it = 0; it < 4; ++it)
                #pragma unroll
                for (int jt = 0; jt < 4; ++jt)
                    acc[it][jt] = __builtin_amdgcn_mfma_f32_16x16x32_bf16(
                        af[it], wf[jt], acc[it][jt], 0, 0, 0);
        }
    }

    // epilogue: C/D layout col=lane&15, row=(lane>>4)*4+reg
    #pragma unroll
    for (int it = 0; it < 4; ++it)
        #pragma unroll
        for (int jt = 0; jt < 4; ++jt) {
            int row = m0 + rw + it * 16 + quad * 4;   // base of 4 consecutive rows
            int col = n0 + cw + jt * 16 + l16;
            float bcol = bias[col];
            float v[4];
            #pragma unroll
            for (int r = 0; r < 4; ++r) {
                v[r] = acc[it][jt][r] + bcol;
                if (RELU) v[r] = fmaxf(v[r], 0.0f);
            }
            if (OMODE == 1) {
                #pragma unroll
                for (int r = 0; r < 4; ++r)
                    ((unsigned short*)Cout)[(size_t)(row + r) * N + col] = f2bf(v[r]);
            } else {   // OMODE == 2: [b,h][dim][key], 4 rows = 4 consecutive keys
                int key = row & (S_ - 1);
                int bb  = row >> 10;
                int hh  = col >> 7, dim = col & (DK_ - 1);
                unsigned short* dst = (unsigned short*)Cout
                    + ((size_t)(bb * H_ + hh) * DK_ + dim) * S_ + key;
                ushort4 o4; o4.x = f2bf(v[0]); o4.y = f2bf(v[1]);
                o4.z = f2bf(v[2]); o4.w = f2bf(v[3]);
                *(ushort4*)dst = o4;
            }
        }
}

// ---------------------------------------------------------------- MFMA flash attention
// Q == K (kq_same). Strict causal (j < q). Row 0 output = 0 (zero_pad).
__global__ __launch_bounds__(256) void attn_mfma(
    const unsigned short* __restrict__ Kbuf, const unsigned short* __restrict__ Vtbuf,
    unsigned short* __restrict__ Obuf)
{
    __shared__ unsigned short sK[64][136];
    __shared__ unsigned short sVt[128][72];
    __shared__ unsigned short sP[4][16][72];

    const int tid  = threadIdx.x;
    const int lane = tid & 63;
    const int w    = tid >> 6;
    const int l16  = lane & 15;
    const int quad = lane >> 4;
    const int qt   = (S_ / 64 - 1) - blockIdx.x;
    const int q0   = qt * 64;
    const int bh   = blockIdx.y;
    const int b    = bh >> 3, h = bh & 7;
    const unsigned short* KB  = Kbuf  + ((size_t)b * S_) * D_ + h * DK_;
    const unsigned short* VTB = Vtbuf + (size_t)bh * DK_ * S_;

    bf16x8 qf[4];
    {
        const unsigned short* qrow = KB + (size_t)(q0 + w * 16 + l16) * D_ + quad * 8;
        #pragma unroll
        for (int ks = 0; ks < 4; ++ks)
            qf[ks] = *(const bf16x8*)(qrow + ks * 32);
    }

    f32x4 Oacc[8] = {};
    float m_run[4] = {-1e30f, -1e30f, -1e30f, -1e30f};
    float l_run[4] = {};
    const float scale = 0.08838834764831845f;

    for (int kt = 0; kt <= qt; ++kt) {
        __syncthreads();
        #pragma unroll
        for (int i = 0; i < 4; ++i) {
            int idx = tid + i * 256;
            int r = idx >> 4, c8 = (idx & 15) * 8;
            *(uint4*)&sK[r][c8] = *(const uint4*)(KB + (size_t)(kt * 64 + r) * D_ + c8);
        }
        #pragma unroll
        for (int i = 0; i < 4; ++i) {
            int idx = tid + i * 256;
            int dim = idx >> 3, k8 = (idx & 7) * 8;
            *(uint4*)&sVt[dim][k8] = *(const uint4*)(VTB + (size_t)dim * S_ + kt * 64 + k8);
        }
        __syncthreads();

        f32x4 sacc[4];
        #pragma unroll
        for (int nt = 0; nt < 4; ++nt) {
            f32x4 a = {};
            #pragma unroll
            for (int ks = 0; ks < 4; ++ks) {
                bf16x8 kf = *(const bf16x8*)&sK[nt * 16 + l16][ks * 32 + quad * 8];
                a = __builtin_amdgcn_mfma_f32_16x16x32_bf16(qf[ks], kf, a, 0, 0, 0);
            }
            sacc[nt] = a;
        }

        const bool diag = (kt == qt);
        #pragma unroll
        for (int nt = 0; nt < 4; ++nt)
            #pragma unroll
            for (int r = 0; r < 4; ++r) {
                float v = sacc[nt][r] * scale;
                if (diag) {
                    int nidx = nt * 16 + l16;
                    int midx = w * 16 + quad * 4 + r;
                    if (nidx >= midx) v = -1e30f;
                }
                sacc[nt][r] = v;
            }

        float alpha[4];
        #pragma unroll
        for (int r = 0; r < 4; ++r) {
            float mx = fmaxf(fmaxf(sacc[0][r], sacc[1][r]), fmaxf(sacc[2][r], sacc[3][r]));
            mx = fmaxf(mx, __shfl_xor(mx, 1));
            mx = fmaxf(mx, __shfl_xor(mx, 2));
            mx = fmaxf(mx, __shfl_xor(mx, 4));
            mx = fmaxf(mx, __shfl_xor(mx, 8));
            float mn = fmaxf(m_run[r], mx);
            alpha[r] = __expf(m_run[r] - mn);
            m_run[r] = mn;
        }
        #pragma unroll
        for (int r = 0; r < 4; ++r) {
            float rs = 0.0f;
            #pragma unroll
            for (int nt = 0; nt < 4; ++nt) {
                float e = __expf(sacc[nt][r] - m_run[r]);
                sacc[nt][r] = e;
                rs += e;
            }
            rs += __shfl_xor(rs, 1);
            rs += __shfl_xor(rs, 2);
            rs += __shfl_xor(rs, 4);
            rs += __shfl_xor(rs, 8);
            l_run[r] = l_run[r] * alpha[r] + rs;
        }
        #pragma unroll
        for (int o = 0; o < 8; ++o)
            #pragma unroll
            for (int r = 0; r < 4; ++r)
                Oacc[o][r] *= alpha[r];

        #pragma unroll
        for (int nt = 0; nt < 4; ++nt)
            #pragma unroll
            for (int r = 0; r < 4; ++r)
                sP[w][quad * 4 + r][nt * 16 + l16] = f2bf(sacc[nt][r]);

        bf16x8 pf[2];
        #pragma unroll
        for (int ks = 0; ks < 2; ++ks)
            pf[ks] = *(const bf16x8*)&sP[w][l16][ks * 32 + quad * 8];
        #pragma unroll
        for (int nt = 0; nt < 8; ++nt) {
            #pragma unroll
            for (int ks = 0; ks < 2; ++ks) {
                bf16x8 vf = *(const bf16x8*)&sVt[nt * 16 + l16][ks * 32 + quad * 8];
                Oacc[nt] = __builtin_amdgcn_mfma_f32_16x16x32_bf16(pf[ks], vf, Oacc[nt], 0, 0, 0);
            }
        }
    }

    float inv[4];
    #pragma unroll
    for (int r = 0; r < 4; ++r) {
        int m = q0 + w * 16 + quad * 4 + r;
        inv[r] = (l_run[r] > 0.0f && m != 0) ? 1.0f / l_run[r] : 0.0f;
    }
    #pragma unroll
    for (int nt = 0; nt < 8; ++nt)
        #pragma unroll
        for (int r = 0; r < 4; ++r) {
            int m = q0 + w * 16 + quad * 4 + r;
            Obuf[((size_t)b * S_ + m) * D_ + h * DK_ + nt * 16 + l16] =
                f2bf(Oacc[nt][r] * inv[r]);
        }
}

// ---------------------------------------------------------------- residual + LayerNorm
__global__ __launch_bounds__(256) void ln_res(
    const float* __restrict__ xin, const unsigned short* __restrict__ delta,
    const float* __restrict__ g, const float* __restrict__ bta,
    float* __restrict__ xout, unsigned short* __restrict__ xbout)
{
    __shared__ float red1[4], red2[4];
    const int row = blockIdx.x;
    const int tid = threadIdx.x;
    const int c = tid * 4;
    const float* xr = xin + (size_t)row * D_;
    const unsigned short* dr = delta + (size_t)row * D_;
    float4 xv = *(const float4*)(xr + c);
    ushort4 du = *(const ushort4*)(dr + c);
    float t0 = xv.x + bf2f(du.x), t1 = xv.y + bf2f(du.y);
    float t2 = xv.z + bf2f(du.z), t3 = xv.w + bf2f(du.w);

    float s = t0 + t1 + t2 + t3;
    #pragma unroll
    for (int off = 32; off > 0; off >>= 1) s += __shfl_down(s, off);
    if ((tid & 63) == 0) red1[tid >> 6] = s;
    __syncthreads();
    float mean = (red1[0] + red1[1] + red1[2] + red1[3]) * (1.0f / 1024.0f);

    float e0 = t0 - mean, e1 = t1 - mean, e2 = t2 - mean, e3 = t3 - mean;
    float ss = e0 * e0 + e1 * e1 + e2 * e2 + e3 * e3;
    #pragma unroll
    for (int off = 32; off > 0; off >>= 1) ss += __shfl_down(ss, off);
    if ((tid & 63) == 0) red2[tid >> 6] = ss;
    __syncthreads();
    float var = (red2[0] + red2[1] + red2[2] + red2[3]) * (1.0f / 1024.0f);
    float rstd = rsqrtf(var + 1e-5f);

    float4 gv = *(const float4*)(g + c);
    float4 bv = *(const float4*)(bta + c);
    float o0 = e0 * rstd * gv.x + bv.x;
    float o1 = e1 * rstd * gv.y + bv.y;
    float o2 = e2 * rstd * gv.z + bv.z;
    float o3 = e3 * rstd * gv.w + bv.w;
    *(float4*)(xout + (size_t)row * D_ + c) = make_float4(o0, o1, o2, o3);
    ushort4 ob; ob.x = f2bf(o0); ob.y = f2bf(o1); ob.z = f2bf(o2); ob.w = f2bf(o3);
    *(ushort4*)(xbout + (size_t)row * D_ + c) = ob;
}

// ---------------------------------------------------------------- driver
extern "C" void kernel_launch(void* const* d_in, const int* in_sizes, int n_in,
                              void* d_out, int out_size, void* d_ws, size_t ws_size,
                              hipStream_t stream)
{
    const float* qe   = (const float*)d_in[0];
    const float* qa   = (const float*)d_in[1];
    const float* pe   = (const float*)d_in[2];
    const float* Wk   = (const float*)d_in[3];
    const float* bk   = (const float*)d_in[4];
    const float* Wv   = (const float*)d_in[5];
    const float* bv   = (const float*)d_in[6];
    const float* Wo   = (const float*)d_in[7];
    const float* bo   = (const float*)d_in[8];
    const float* ln1g = (const float*)d_in[9];
    const float* ln1b = (const float*)d_in[10];
    const float* W1   = (const float*)d_in[11];
    const float* b1   = (const float*)d_in[12];
    const float* W2   = (const float*)d_in[13];
    const float* b2   = (const float*)d_in[14];
    const float* ln2g = (const float*)d_in[15];
    const float* ln2b = (const float*)d_in[16];

    const size_t BSD = (size_t)B_ * S_ * D_;
    const size_t BSF = (size_t)B_ * S_ * FF_;
    const size_t WDD = (size_t)D_ * D_;        // 1M elements (one layer's DxD weight)
    const size_t WFD = (size_t)FF_ * D_;       // 4M elements (one layer's FFN weight)

    // ws layout (~160 MB): x32 33.5 | xb 16.8 | yb 16.8 | delta 16.8 |
    //   union 67.1 {Kb,Vt,attnb | hb} | wslot 8.4 (bf16 weight staging, reused per GEMM)
    char* p = (char*)d_ws;
    auto take = [&](size_t bytes) { char* r = p; p += (bytes + 255) & ~255ULL; return r; };
    float*          x32   = (float*)take(BSD * 4);
    unsigned short* xb    = (unsigned short*)take(BSD * 2);
    unsigned short* yb    = (unsigned short*)take(BSD * 2);
    unsigned short* delta = (unsigned short*)take(BSD * 2);
    char*           uni   = take(BSF * 2);
    unsigned short* Kb    = (unsigned short*)uni;
    unsigned short* Vt    = Kb + BSD;
    unsigned short* attnb = Vt + BSD;
    unsigned short* hb    = (unsigned short*)uni;
    unsigned short* wslot = (unsigned short*)take(WFD * 2);

    init_xy<<<(int)(BSD / 4 / 256), 256, 0, stream>>>(qe, qa, pe, x32, xb, yb);

    const int M = B_ * S_;
    for (int l = 0; l < L_; ++l) {
        cvt_bf16<<<(int)(WDD / 1024), 256, 0, stream>>>(Wk + l * WDD, wslot);
        gemm_bt<false, 1><<<dim3(D_ / 128, M / 128), 256, 0, stream>>>(
            xb, wslot, bk + l * D_, Kb, M, D_, D_);
        cvt_bf16<<<(int)(WDD / 1024), 256, 0, stream>>>(Wv + l * WDD, wslot);
        gemm_bt<false, 2><<<dim3(D_ / 128, M / 128), 256, 0, stream>>>(
            yb, wslot, bv + l * D_, Vt, M, D_, D_);
        attn_mfma<<<dim3(S_ / 64, B_ * H_), 256, 0, stream>>>(Kb, Vt, attnb);
        cvt_bf16<<<(int)(WDD / 1024), 256, 0, stream>>>(Wo + l * WDD, wslot);
        gemm_bt<false, 1><<<dim3(D_ / 128, M / 128), 256, 0, stream>>>(
            attnb, wslot, bo + l * D_, delta, M, D_, D_);
        ln_res<<<M, 256, 0, stream>>>(x32, delta, ln1g + l * D_, ln1b + l * D_, x32, xb);
        cvt_bf16<<<(int)(WFD / 1024), 256, 0, stream>>>(W1 + l * WFD, wslot);
        gemm_bt<true, 1><<<dim3(FF_ / 128, M / 128), 256, 0, stream>>>(
            xb, wslot, b1 + l * FF_, hb, M, FF_, D_);
        cvt_bf16<<<(int)(WFD / 1024), 256, 0, stream>>>(W2 + l * WFD, wslot);
        gemm_bt<false, 1><<<dim3(D_ / 128, M / 128), 256, 0, stream>>>(
            hb, wslot, b2 + l * D_, delta, M, D_, FF_);
        float* xo = (l == L_ - 1) ? (float*)d_out : x32;
        ln_res<<<M, 256, 0, stream>>>(x32, delta, ln2g + l * D_, ln2b + l * D_, xo, xb);
    }
}

// Round 5
// 990.116 us; speedup vs baseline: 2.5483x; 1.0922x over previous
//
#include <hip/hip_runtime.h>
#include <hip/hip_bf16.h>
#include <cstdint>
#include <cstddef>

#define B_  8
#define S_  1024
#define D_  1024
#define H_  8
#define FF_ 4096
#define L_  2
#define DK_ 128

typedef __bf16 bf16x8 __attribute__((ext_vector_type(8)));
typedef float  f32x4  __attribute__((ext_vector_type(4)));

__device__ __forceinline__ unsigned short f2bf(float f) {
    union { float f; uint32_t u; } v; v.f = f;
    uint32_t r = v.u + 0x7fffu + ((v.u >> 16) & 1u);
    return (unsigned short)(r >> 16);
}
__device__ __forceinline__ float bf2f(unsigned short u) {
    union { uint32_t u; float f; } v; v.u = ((uint32_t)u) << 16; return v.f;
}

// ---------------------------------------------------------------- init: x = qe+pe, y = qa+pe
__global__ __launch_bounds__(256) void init_xy(
    const float* __restrict__ qe, const float* __restrict__ qa,
    const float* __restrict__ pe,
    float* __restrict__ x32, unsigned short* __restrict__ xb,
    unsigned short* __restrict__ yb)
{
    int i = (blockIdx.x * 256 + threadIdx.x) * 4;
    int pi = i & (S_ * D_ - 1);
    float4 q = *(const float4*)(qe + i);
    float4 a = *(const float4*)(qa + i);
    float4 p = *(const float4*)(pe + pi);
    float x0 = q.x + p.x, x1 = q.y + p.y, x2 = q.z + p.z, x3 = q.w + p.w;
    float y0 = a.x + p.x, y1 = a.y + p.y, y2 = a.z + p.z, y3 = a.w + p.w;
    *(float4*)(x32 + i) = make_float4(x0, x1, x2, x3);
    ushort4 xo; xo.x = f2bf(x0); xo.y = f2bf(x1); xo.z = f2bf(x2); xo.w = f2bf(x3);
    ushort4 yo; yo.x = f2bf(y0); yo.y = f2bf(y1); yo.z = f2bf(y2); yo.w = f2bf(y3);
    *(ushort4*)(xb + i) = xo;
    *(ushort4*)(yb + i) = yo;
}

// ---------------------------------------------------------------- fp32 -> bf16 weight convert
__global__ __launch_bounds__(256) void cvt_bf16(
    const float* __restrict__ in, unsigned short* __restrict__ out)
{
    int i = (blockIdx.x * 256 + threadIdx.x) * 4;
    float4 f = *(const float4*)(in + i);
    ushort4 o; o.x = f2bf(f.x); o.y = f2bf(f.y); o.z = f2bf(f.z); o.w = f2bf(f.w);
    *(ushort4*)(out + i) = o;
}

// ---------------------------------------------------------------- m97-style bf16 MFMA NT-GEMM
// C[m,n] = sum_k A[m,k] * W[n,k] + bias[n]   (A: MxK bf16, W: NxK bf16)
// 128x128 tile, BK=64, 4 waves (2x2) each computing 4x4 of 16x16x32 MFMA.
// global_load_lds width=16 staging; XOR-chunk swizzle (chunk^row&7) kills bank conflicts.
// OMODE: 1 = bf16 row-major out; 2 = bf16 per-head-transposed out [b,h][dim][key]
template<bool RELU, int OMODE>
__global__ __launch_bounds__(256) void gemm_bt(
    const unsigned short* __restrict__ A, const unsigned short* __restrict__ W,
    const float* __restrict__ bias, void* __restrict__ Cout,
    int M, int N, int K)
{
    __shared__ unsigned short sA[128][64];
    __shared__ unsigned short sW[128][64];

    const int tid  = threadIdx.x;
    const int lane = tid & 63;
    const int w    = tid >> 6;
    const int l16  = lane & 15;
    const int quad = lane >> 4;
    const int m0 = blockIdx.y * 128;
    const int n0 = blockIdx.x * 128;
    const int rw = (w >> 1) * 64;
    const int cw = (w & 1) * 64;

    const int srow   = lane >> 3;
    const int schunk = lane & 7;

    f32x4 acc[4][4] = {};

    for (int k0 = 0; k0 < K; k0 += 64) {
        __syncthreads();
        #pragma unroll
        for (int i = 0; i < 4; ++i) {
            int r0  = w * 32 + i * 8;
            int row = r0 + srow;
            int gc  = schunk ^ (row & 7);
            const unsigned short* ga = A + (size_t)(m0 + row) * K + k0 + gc * 8;
            const unsigned short* gw = W + (size_t)(n0 + row) * K + k0 + gc * 8;
            __builtin_amdgcn_global_load_lds(
                (const __attribute__((address_space(1))) unsigned int*)ga,
                (__attribute__((address_space(3))) unsigned int*)&sA[r0][0], 16, 0, 0);
            __builtin_amdgcn_global_load_lds(
                (const __attribute__((address_space(1))) unsigned int*)gw,
                (__attribute__((address_space(3))) unsigned int*)&sW[r0][0], 16, 0, 0);
        }
        __syncthreads();

        #pragma unroll
        for (int ks = 0; ks < 2; ++ks) {
            bf16x8 af[4], wf[4];
            #pragma unroll
            for (int t = 0; t < 4; ++t) {
                int arow = rw + t * 16 + l16;
                int achk = (ks * 4 + quad) ^ (arow & 7);
                af[t] = *(const bf16x8*)&sA[arow][achk * 8];
                int wrow = cw + t * 16 + l16;
                int wchk = (ks * 4 + quad) ^ (wrow & 7);
                wf[t] = *(const bf16x8*)&sW[wrow][wchk * 8];
            }
            #pragma unroll
            for (int it = 0; it < 4; ++it)
                #pragma unroll
                for (int jt = 0; jt < 4; ++jt)
                    acc[it][jt] = __builtin_amdgcn_mfma_f32_16x16x32_bf16(
                        af[it], wf[jt], acc[it][jt], 0, 0, 0);
        }
    }

    #pragma unroll
    for (int it = 0; it < 4; ++it)
        #pragma unroll
        for (int jt = 0; jt < 4; ++jt) {
            int row = m0 + rw + it * 16 + quad * 4;
            int col = n0 + cw + jt * 16 + l16;
            float bcol = bias[col];
            float v[4];
            #pragma unroll
            for (int r = 0; r < 4; ++r) {
                v[r] = acc[it][jt][r] + bcol;
                if (RELU) v[r] = fmaxf(v[r], 0.0f);
            }
            if (OMODE == 1) {
                #pragma unroll
                for (int r = 0; r < 4; ++r)
                    ((unsigned short*)Cout)[(size_t)(row + r) * N + col] = f2bf(v[r]);
            } else {
                int key = row & (S_ - 1);
                int bb  = row >> 10;
                int hh  = col >> 7, dim = col & (DK_ - 1);
                unsigned short* dst = (unsigned short*)Cout
                    + ((size_t)(bb * H_ + hh) * DK_ + dim) * S_ + key;
                ushort4 o4; o4.x = f2bf(v[0]); o4.y = f2bf(v[1]);
                o4.z = f2bf(v[2]); o4.w = f2bf(v[3]);
                *(ushort4*)dst = o4;
            }
        }
}

// ---------------------------------------------------------------- MFMA flash attention
// Q == K (kq_same). Strict causal (j < q). Row 0 output = 0 (zero_pad).
// Balanced pairing: block pa handles q-tiles {15-pa, pa} -> uniform 17 k-iters/block.
// Register-prefetch pipeline: next K/Vt tile loaded to VGPRs during current compute.
__global__ __launch_bounds__(256) void attn_mfma(
    const unsigned short* __restrict__ Kbuf, const unsigned short* __restrict__ Vtbuf,
    unsigned short* __restrict__ Obuf)
{
    __shared__ unsigned short sK[64][136];
    __shared__ unsigned short sVt[128][72];
    __shared__ unsigned short sP[4][16][72];

    const int tid  = threadIdx.x;
    const int lane = tid & 63;
    const int w    = tid >> 6;
    const int l16  = lane & 15;
    const int quad = lane >> 4;
    const int pa   = blockIdx.x;                 // 0..7
    const int bh   = blockIdx.y;
    const int b    = bh >> 3, h = bh & 7;
    const unsigned short* KB  = Kbuf  + ((size_t)b * S_) * D_ + h * DK_;
    const unsigned short* VTB = Vtbuf + (size_t)bh * DK_ * S_;

    // staging decomposition (fixed per thread)
    const int skr = tid >> 4, skc = (tid & 15) * 8;   // K: rows skr+{0,16,32,48}, col skc
    const int svr = tid >> 3, svc = (tid & 7) * 8;    // Vt: rows svr+{0,32,64,96}, col svc

    uint4 pk[4], pv[4];
    const float scale = 0.08838834764831845f;    // 1/sqrt(128)

    #pragma unroll
    for (int half = 0; half < 2; ++half) {
        const int qt = half == 0 ? (15 - pa) : pa;
        const int q0 = qt * 64;

        // Q fragments (A-layout), registers
        bf16x8 qf[4];
        {
            const unsigned short* qrow = KB + (size_t)(q0 + w * 16 + l16) * D_ + quad * 8;
            #pragma unroll
            for (int ks = 0; ks < 4; ++ks)
                qf[ks] = *(const bf16x8*)(qrow + ks * 32);
        }

        f32x4 Oacc[8] = {};
        float m_run[4] = {-1e30f, -1e30f, -1e30f, -1e30f};
        float l_run[4] = {};

        // prefetch tile 0
        #pragma unroll
        for (int i = 0; i < 4; ++i) {
            pk[i] = *(const uint4*)(KB + (size_t)(skr + i * 16) * D_ + skc);
            pv[i] = *(const uint4*)(VTB + (size_t)(svr + i * 32) * S_ + svc);
        }

        for (int kt = 0; kt <= qt; ++kt) {
            __syncthreads();                     // previous iter's LDS readers done
            #pragma unroll
            for (int i = 0; i < 4; ++i) {
                *(uint4*)&sK[skr + i * 16][skc] = pk[i];
                *(uint4*)&sVt[svr + i * 32][svc] = pv[i];
            }
            __syncthreads();
            if (kt < qt) {
                int kn = (kt + 1) * 64;
                #pragma unroll
                for (int i = 0; i < 4; ++i) {
                    pk[i] = *(const uint4*)(KB + (size_t)(kn + skr + i * 16) * D_ + skc);
                    pv[i] = *(const uint4*)(VTB + (size_t)(svr + i * 32) * S_ + kn + svc);
                }
            }

            // S = Q K^T
            f32x4 sacc[4];
            #pragma unroll
            for (int nt = 0; nt < 4; ++nt) {
                f32x4 a = {};
                #pragma unroll
                for (int ks = 0; ks < 4; ++ks) {
                    bf16x8 kf = *(const bf16x8*)&sK[nt * 16 + l16][ks * 32 + quad * 8];
                    a = __builtin_amdgcn_mfma_f32_16x16x32_bf16(qf[ks], kf, a, 0, 0, 0);
                }
                sacc[nt] = a;
            }

            const bool diag = (kt == qt);
            #pragma unroll
            for (int nt = 0; nt < 4; ++nt)
                #pragma unroll
                for (int r = 0; r < 4; ++r) {
                    float v = sacc[nt][r] * scale;
                    if (diag) {
                        int nidx = nt * 16 + l16;
                        int midx = w * 16 + quad * 4 + r;
                        if (nidx >= midx) v = -1e30f;
                    }
                    sacc[nt][r] = v;
                }

            float alpha[4];
            #pragma unroll
            for (int r = 0; r < 4; ++r) {
                float mx = fmaxf(fmaxf(sacc[0][r], sacc[1][r]), fmaxf(sacc[2][r], sacc[3][r]));
                mx = fmaxf(mx, __shfl_xor(mx, 1));
                mx = fmaxf(mx, __shfl_xor(mx, 2));
                mx = fmaxf(mx, __shfl_xor(mx, 4));
                mx = fmaxf(mx, __shfl_xor(mx, 8));
                float mn = fmaxf(m_run[r], mx);
                alpha[r] = __expf(m_run[r] - mn);
                m_run[r] = mn;
            }
            #pragma unroll
            for (int r = 0; r < 4; ++r) {
                float rs = 0.0f;
                #pragma unroll
                for (int nt = 0; nt < 4; ++nt) {
                    float e = __expf(sacc[nt][r] - m_run[r]);
                    sacc[nt][r] = e;
                    rs += e;
                }
                rs += __shfl_xor(rs, 1);
                rs += __shfl_xor(rs, 2);
                rs += __shfl_xor(rs, 4);
                rs += __shfl_xor(rs, 8);
                l_run[r] = l_run[r] * alpha[r] + rs;
            }
            #pragma unroll
            for (int o = 0; o < 8; ++o)
                #pragma unroll
                for (int r = 0; r < 4; ++r)
                    Oacc[o][r] *= alpha[r];

            // P (C/D layout) -> LDS (A-layout), wave-private
            #pragma unroll
            for (int nt = 0; nt < 4; ++nt)
                #pragma unroll
                for (int r = 0; r < 4; ++r)
                    sP[w][quad * 4 + r][nt * 16 + l16] = f2bf(sacc[nt][r]);

            bf16x8 pf[2];
            #pragma unroll
            for (int ks = 0; ks < 2; ++ks)
                pf[ks] = *(const bf16x8*)&sP[w][l16][ks * 32 + quad * 8];
            #pragma unroll
            for (int nt = 0; nt < 8; ++nt) {
                #pragma unroll
                for (int ks = 0; ks < 2; ++ks) {
                    bf16x8 vf = *(const bf16x8*)&sVt[nt * 16 + l16][ks * 32 + quad * 8];
                    Oacc[nt] = __builtin_amdgcn_mfma_f32_16x16x32_bf16(pf[ks], vf, Oacc[nt], 0, 0, 0);
                }
            }
        }

        // finalize: O *= 1/l  (0 for empty rows and the zero_pad row q==0)
        float inv[4];
        #pragma unroll
        for (int r = 0; r < 4; ++r) {
            int m = q0 + w * 16 + quad * 4 + r;
            inv[r] = (l_run[r] > 0.0f && m != 0) ? 1.0f / l_run[r] : 0.0f;
        }
        #pragma unroll
        for (int nt = 0; nt < 8; ++nt)
            #pragma unroll
            for (int r = 0; r < 4; ++r) {
                int m = q0 + w * 16 + quad * 4 + r;
                Obuf[((size_t)b * S_ + m) * D_ + h * DK_ + nt * 16 + l16] =
                    f2bf(Oacc[nt][r] * inv[r]);
            }
    }
}

// ---------------------------------------------------------------- residual + LayerNorm
__global__ __launch_bounds__(256) void ln_res(
    const float* __restrict__ xin, const unsigned short* __restrict__ delta,
    const float* __restrict__ g, const float* __restrict__ bta,
    float* __restrict__ xout, unsigned short* __restrict__ xbout)
{
    __shared__ float red1[4], red2[4];
    const int row = blockIdx.x;
    const int tid = threadIdx.x;
    const int c = tid * 4;
    const float* xr = xin + (size_t)row * D_;
    const unsigned short* dr = delta + (size_t)row * D_;
    float4 xv = *(const float4*)(xr + c);
    ushort4 du = *(const ushort4*)(dr + c);
    float t0 = xv.x + bf2f(du.x), t1 = xv.y + bf2f(du.y);
    float t2 = xv.z + bf2f(du.z), t3 = xv.w + bf2f(du.w);

    float s = t0 + t1 + t2 + t3;
    #pragma unroll
    for (int off = 32; off > 0; off >>= 1) s += __shfl_down(s, off);
    if ((tid & 63) == 0) red1[tid >> 6] = s;
    __syncthreads();
    float mean = (red1[0] + red1[1] + red1[2] + red1[3]) * (1.0f / 1024.0f);

    float e0 = t0 - mean, e1 = t1 - mean, e2 = t2 - mean, e3 = t3 - mean;
    float ss = e0 * e0 + e1 * e1 + e2 * e2 + e3 * e3;
    #pragma unroll
    for (int off = 32; off > 0; off >>= 1) ss += __shfl_down(ss, off);
    if ((tid & 63) == 0) red2[tid >> 6] = ss;
    __syncthreads();
    float var = (red2[0] + red2[1] + red2[2] + red2[3]) * (1.0f / 1024.0f);
    float rstd = rsqrtf(var + 1e-5f);

    float4 gv = *(const float4*)(g + c);
    float4 bv = *(const float4*)(bta + c);
    float o0 = e0 * rstd * gv.x + bv.x;
    float o1 = e1 * rstd * gv.y + bv.y;
    float o2 = e2 * rstd * gv.z + bv.z;
    float o3 = e3 * rstd * gv.w + bv.w;
    *(float4*)(xout + (size_t)row * D_ + c) = make_float4(o0, o1, o2, o3);
    ushort4 ob; ob.x = f2bf(o0); ob.y = f2bf(o1); ob.z = f2bf(o2); ob.w = f2bf(o3);
    *(ushort4*)(xbout + (size_t)row * D_ + c) = ob;
}

// ---------------------------------------------------------------- driver
extern "C" void kernel_launch(void* const* d_in, const int* in_sizes, int n_in,
                              void* d_out, int out_size, void* d_ws, size_t ws_size,
                              hipStream_t stream)
{
    const float* qe   = (const float*)d_in[0];
    const float* qa   = (const float*)d_in[1];
    const float* pe   = (const float*)d_in[2];
    const float* Wk   = (const float*)d_in[3];
    const float* bk   = (const float*)d_in[4];
    const float* Wv   = (const float*)d_in[5];
    const float* bv   = (const float*)d_in[6];
    const float* Wo   = (const float*)d_in[7];
    const float* bo   = (const float*)d_in[8];
    const float* ln1g = (const float*)d_in[9];
    const float* ln1b = (const float*)d_in[10];
    const float* W1   = (const float*)d_in[11];
    const float* b1   = (const float*)d_in[12];
    const float* W2   = (const float*)d_in[13];
    const float* b2   = (const float*)d_in[14];
    const float* ln2g = (const float*)d_in[15];
    const float* ln2b = (const float*)d_in[16];

    const size_t BSD = (size_t)B_ * S_ * D_;
    const size_t BSF = (size_t)B_ * S_ * FF_;
    const size_t WDD = (size_t)D_ * D_;
    const size_t WFD = (size_t)FF_ * D_;

    char* p = (char*)d_ws;
    auto take = [&](size_t bytes) { char* r = p; p += (bytes + 255) & ~255ULL; return r; };
    float*          x32   = (float*)take(BSD * 4);
    unsigned short* xb    = (unsigned short*)take(BSD * 2);
    unsigned short* yb    = (unsigned short*)take(BSD * 2);
    unsigned short* delta = (unsigned short*)take(BSD * 2);
    char*           uni   = take(BSF * 2);
    unsigned short* Kb    = (unsigned short*)uni;
    unsigned short* Vt    = Kb + BSD;
    unsigned short* attnb = Vt + BSD;
    unsigned short* hb    = (unsigned short*)uni;
    unsigned short* wslot = (unsigned short*)take(WFD * 2);

    init_xy<<<(int)(BSD / 4 / 256), 256, 0, stream>>>(qe, qa, pe, x32, xb, yb);

    const int M = B_ * S_;
    for (int l = 0; l < L_; ++l) {
        cvt_bf16<<<(int)(WDD / 1024), 256, 0, stream>>>(Wk + l * WDD, wslot);
        gemm_bt<false, 1><<<dim3(D_ / 128, M / 128), 256, 0, stream>>>(
            xb, wslot, bk + l * D_, Kb, M, D_, D_);
        cvt_bf16<<<(int)(WDD / 1024), 256, 0, stream>>>(Wv + l * WDD, wslot);
        gemm_bt<false, 2><<<dim3(D_ / 128, M / 128), 256, 0, stream>>>(
            yb, wslot, bv + l * D_, Vt, M, D_, D_);
        attn_mfma<<<dim3(8, B_ * H_), 256, 0, stream>>>(Kb, Vt, attnb);
        cvt_bf16<<<(int)(WDD / 1024), 256, 0, stream>>>(Wo + l * WDD, wslot);
        gemm_bt<false, 1><<<dim3(D_ / 128, M / 128), 256, 0, stream>>>(
            attnb, wslot, bo + l * D_, delta, M, D_, D_);
        ln_res<<<M, 256, 0, stream>>>(x32, delta, ln1g + l * D_, ln1b + l * D_, x32, xb);
        cvt_bf16<<<(int)(WFD / 1024), 256, 0, stream>>>(W1 + l * WFD, wslot);
        gemm_bt<true, 1><<<dim3(FF_ / 128, M / 128), 256, 0, stream>>>(
            xb, wslot, b1 + l * FF_, hb, M, FF_, D_);
        cvt_bf16<<<(int)(WFD / 1024), 256, 0, stream>>>(W2 + l * WFD, wslot);
        gemm_bt<false, 1><<<dim3(D_ / 128, M / 128), 256, 0, stream>>>(
            hb, wslot, b2 + l * D_, delta, M, D_, FF_);
        float* xo = (l == L_ - 1) ? (float*)d_out : x32;
        ln_res<<<M, 256, 0, stream>>>(x32, delta, ln2g + l * D_, ln2b + l * D_, xo, xb);
    }
}

// Round 6
// 912.349 us; speedup vs baseline: 2.7655x; 1.0852x over previous
//
#include <hip/hip_runtime.h>
#include <hip/hip_bf16.h>
#include <cstdint>
#include <cstddef>

#define B_  8
#define S_  1024
#define D_  1024
#define H_  8
#define FF_ 4096
#define L_  2
#define DK_ 128

typedef __bf16 bf16x8 __attribute__((ext_vector_type(8)));
typedef float  f32x4  __attribute__((ext_vector_type(4)));

__device__ __forceinline__ unsigned short f2bf(float f) {
    union { float f; uint32_t u; } v; v.f = f;
    uint32_t r = v.u + 0x7fffu + ((v.u >> 16) & 1u);
    return (unsigned short)(r >> 16);
}
__device__ __forceinline__ float bf2f(unsigned short u) {
    union { uint32_t u; float f; } v; v.u = ((uint32_t)u) << 16; return v.f;
}

// ---------------------------------------------------------------- init: x = qe+pe, y = qa+pe
__global__ __launch_bounds__(256) void init_xy(
    const float* __restrict__ qe, const float* __restrict__ qa,
    const float* __restrict__ pe,
    float* __restrict__ x32, unsigned short* __restrict__ xb,
    unsigned short* __restrict__ yb)
{
    int i = (blockIdx.x * 256 + threadIdx.x) * 4;
    int pi = i & (S_ * D_ - 1);
    float4 q = *(const float4*)(qe + i);
    float4 a = *(const float4*)(qa + i);
    float4 p = *(const float4*)(pe + pi);
    float x0 = q.x + p.x, x1 = q.y + p.y, x2 = q.z + p.z, x3 = q.w + p.w;
    float y0 = a.x + p.x, y1 = a.y + p.y, y2 = a.z + p.z, y3 = a.w + p.w;
    *(float4*)(x32 + i) = make_float4(x0, x1, x2, x3);
    ushort4 xo; xo.x = f2bf(x0); xo.y = f2bf(x1); xo.z = f2bf(x2); xo.w = f2bf(x3);
    ushort4 yo; yo.x = f2bf(y0); yo.y = f2bf(y1); yo.z = f2bf(y2); yo.w = f2bf(y3);
    *(ushort4*)(xb + i) = xo;
    *(ushort4*)(yb + i) = yo;
}

// ---------------------------------------------------------------- fp32 -> bf16 weight convert
__global__ __launch_bounds__(256) void cvt_bf16(
    const float* __restrict__ in, unsigned short* __restrict__ out)
{
    int i = (blockIdx.x * 256 + threadIdx.x) * 4;
    float4 f = *(const float4*)(in + i);
    ushort4 o; o.x = f2bf(f.x); o.y = f2bf(f.y); o.z = f2bf(f.z); o.w = f2bf(f.w);
    *(ushort4*)(out + i) = o;
}

// ---------------------------------------------------------------- m97-style bf16 MFMA NT-GEMM
// C[m,n] = sum_k A[m,k] * W[n,k] + bias[n]   (A: MxK bf16, W: NxK bf16)
// 128x128 tile, BK=64, 4 waves (2x2) each computing 4x4 of 16x16x32 MFMA.
// global_load_lds width=16 staging; XOR-chunk swizzle (chunk^row&7) kills bank conflicts.
// OMODE: 1 = bf16 row-major out; 2 = bf16 per-head-transposed out [b,h][dim][key]
template<bool RELU, int OMODE>
__global__ __launch_bounds__(256) void gemm_bt(
    const unsigned short* __restrict__ A, const unsigned short* __restrict__ W,
    const float* __restrict__ bias, void* __restrict__ Cout,
    int M, int N, int K)
{
    __shared__ unsigned short sA[128][64];
    __shared__ unsigned short sW[128][64];

    const int tid  = threadIdx.x;
    const int lane = tid & 63;
    const int w    = tid >> 6;
    const int l16  = lane & 15;
    const int quad = lane >> 4;
    const int m0 = blockIdx.y * 128;
    const int n0 = blockIdx.x * 128;
    const int rw = (w >> 1) * 64;
    const int cw = (w & 1) * 64;

    const int srow   = lane >> 3;
    const int schunk = lane & 7;

    f32x4 acc[4][4] = {};

    for (int k0 = 0; k0 < K; k0 += 64) {
        __syncthreads();
        #pragma unroll
        for (int i = 0; i < 4; ++i) {
            int r0  = w * 32 + i * 8;
            int row = r0 + srow;
            int gc  = schunk ^ (row & 7);
            const unsigned short* ga = A + (size_t)(m0 + row) * K + k0 + gc * 8;
            const unsigned short* gw = W + (size_t)(n0 + row) * K + k0 + gc * 8;
            __builtin_amdgcn_global_load_lds(
                (const __attribute__((address_space(1))) unsigned int*)ga,
                (__attribute__((address_space(3))) unsigned int*)&sA[r0][0], 16, 0, 0);
            __builtin_amdgcn_global_load_lds(
                (const __attribute__((address_space(1))) unsigned int*)gw,
                (__attribute__((address_space(3))) unsigned int*)&sW[r0][0], 16, 0, 0);
        }
        __syncthreads();

        #pragma unroll
        for (int ks = 0; ks < 2; ++ks) {
            bf16x8 af[4], wf[4];
            #pragma unroll
            for (int t = 0; t < 4; ++t) {
                int arow = rw + t * 16 + l16;
                int achk = (ks * 4 + quad) ^ (arow & 7);
                af[t] = *(const bf16x8*)&sA[arow][achk * 8];
                int wrow = cw + t * 16 + l16;
                int wchk = (ks * 4 + quad) ^ (wrow & 7);
                wf[t] = *(const bf16x8*)&sW[wrow][wchk * 8];
            }
            #pragma unroll
            for (int it = 0; it < 4; ++it)
                #pragma unroll
                for (int jt = 0; jt < 4; ++jt)
                    acc[it][jt] = __builtin_amdgcn_mfma_f32_16x16x32_bf16(
                        af[it], wf[jt], acc[it][jt], 0, 0, 0);
        }
    }

    #pragma unroll
    for (int it = 0; it < 4; ++it)
        #pragma unroll
        for (int jt = 0; jt < 4; ++jt) {
            int row = m0 + rw + it * 16 + quad * 4;
            int col = n0 + cw + jt * 16 + l16;
            float bcol = bias[col];
            float v[4];
            #pragma unroll
            for (int r = 0; r < 4; ++r) {
                v[r] = acc[it][jt][r] + bcol;
                if (RELU) v[r] = fmaxf(v[r], 0.0f);
            }
            if (OMODE == 1) {
                #pragma unroll
                for (int r = 0; r < 4; ++r)
                    ((unsigned short*)Cout)[(size_t)(row + r) * N + col] = f2bf(v[r]);
            } else {
                int key = row & (S_ - 1);
                int bb  = row >> 10;
                int hh  = col >> 7, dim = col & (DK_ - 1);
                unsigned short* dst = (unsigned short*)Cout
                    + ((size_t)(bb * H_ + hh) * DK_ + dim) * S_ + key;
                ushort4 o4; o4.x = f2bf(v[0]); o4.y = f2bf(v[1]);
                o4.z = f2bf(v[2]); o4.w = f2bf(v[3]);
                *(ushort4*)dst = o4;
            }
        }
}

// ---------------------------------------------------------------- MFMA flash attention
// Q == K (kq_same). Strict causal (j < q). Row 0 output = 0 (zero_pad).
// Balanced pairing: block pa handles q-tiles {15-pa, pa} -> uniform 17 k-iters/block.
// Double-buffered global_load_lds staging (no VGPR prefetch -> no spill);
// XOR-chunk swizzle on K (chunk^row&15) and Vt (chunk^row&7) for conflict-free reads.
__global__ __launch_bounds__(256) void attn_mfma(
    const unsigned short* __restrict__ Kbuf, const unsigned short* __restrict__ Vtbuf,
    unsigned short* __restrict__ Obuf)
{
    __shared__ unsigned short sK[2][64][128];    // 2 x 16 KB
    __shared__ unsigned short sVt[2][128][64];   // 2 x 16 KB
    __shared__ unsigned short sP[4][16][72];     // 9.2 KB

    const int tid  = threadIdx.x;
    const int lane = tid & 63;
    const int w    = tid >> 6;
    const int l16  = lane & 15;
    const int quad = lane >> 4;
    const int pa   = blockIdx.x;                 // 0..7
    const int bh   = blockIdx.y;
    const int b    = bh >> 3, h = bh & 7;
    const unsigned short* KB  = Kbuf  + ((size_t)b * S_) * D_ + h * DK_;
    const unsigned short* VTB = Vtbuf + (size_t)bh * DK_ * S_;

    const float scale = 0.08838834764831845f;    // 1/sqrt(128)

    // issue direct global->LDS DMA for k-tile kt into buffer buf
    auto stage = [&](int kt, int buf) {
        #pragma unroll
        for (int i = 0; i < 4; ++i) {            // K: 64 rows x 256B, 4 rows/wave/inst
            int r0  = w * 16 + i * 4;
            int row = r0 + (lane >> 4);
            int c   = (lane & 15) ^ (row & 15);
            const unsigned short* g = KB + (size_t)(kt * 64 + row) * D_ + c * 8;
            __builtin_amdgcn_global_load_lds(
                (const __attribute__((address_space(1))) unsigned int*)g,
                (__attribute__((address_space(3))) unsigned int*)&sK[buf][r0][0], 16, 0, 0);
        }
        #pragma unroll
        for (int i = 0; i < 4; ++i) {            // Vt: 128 rows x 128B, 8 rows/wave/inst
            int r0  = w * 32 + i * 8;
            int row = r0 + (lane >> 3);
            int c   = (lane & 7) ^ (row & 7);
            const unsigned short* g = VTB + (size_t)row * S_ + kt * 64 + c * 8;
            __builtin_amdgcn_global_load_lds(
                (const __attribute__((address_space(1))) unsigned int*)g,
                (__attribute__((address_space(3))) unsigned int*)&sVt[buf][r0][0], 16, 0, 0);
        }
    };

    #pragma unroll
    for (int half = 0; half < 2; ++half) {
        const int qt = half == 0 ? (15 - pa) : pa;
        const int q0 = qt * 64;

        // Q fragments (A-layout), registers
        bf16x8 qf[4];
        {
            const unsigned short* qrow = KB + (size_t)(q0 + w * 16 + l16) * D_ + quad * 8;
            #pragma unroll
            for (int ks = 0; ks < 4; ++ks)
                qf[ks] = *(const bf16x8*)(qrow + ks * 32);
        }

        f32x4 Oacc[8] = {};
        float m_run[4] = {-1e30f, -1e30f, -1e30f, -1e30f};
        float l_run[4] = {};

        int cur = 0;
        stage(0, cur);                           // preload tile 0

        for (int kt = 0; kt <= qt; ++kt) {
            __syncthreads();                     // drains tile-kt DMA; prev readers done
            if (kt < qt) stage(kt + 1, cur ^ 1); // prefetch lands during compute below

            // S = Q K^T
            f32x4 sacc[4];
            #pragma unroll
            for (int nt = 0; nt < 4; ++nt) {
                f32x4 a = {};
                #pragma unroll
                for (int ks = 0; ks < 4; ++ks) {
                    int kr = nt * 16 + l16;
                    int p  = (ks * 4 + quad) ^ (kr & 15);
                    bf16x8 kf = *(const bf16x8*)&sK[cur][kr][p * 8];
                    a = __builtin_amdgcn_mfma_f32_16x16x32_bf16(qf[ks], kf, a, 0, 0, 0);
                }
                sacc[nt] = a;
            }

            const bool diag = (kt == qt);
            #pragma unroll
            for (int nt = 0; nt < 4; ++nt)
                #pragma unroll
                for (int r = 0; r < 4; ++r) {
                    float v = sacc[nt][r] * scale;
                    if (diag) {
                        int nidx = nt * 16 + l16;
                        int midx = w * 16 + quad * 4 + r;
                        if (nidx >= midx) v = -1e30f;
                    }
                    sacc[nt][r] = v;
                }

            float alpha[4];
            #pragma unroll
            for (int r = 0; r < 4; ++r) {
                float mx = fmaxf(fmaxf(sacc[0][r], sacc[1][r]), fmaxf(sacc[2][r], sacc[3][r]));
                mx = fmaxf(mx, __shfl_xor(mx, 1));
                mx = fmaxf(mx, __shfl_xor(mx, 2));
                mx = fmaxf(mx, __shfl_xor(mx, 4));
                mx = fmaxf(mx, __shfl_xor(mx, 8));
                float mn = fmaxf(m_run[r], mx);
                alpha[r] = __expf(m_run[r] - mn);
                m_run[r] = mn;
            }
            #pragma unroll
            for (int r = 0; r < 4; ++r) {
                float rs = 0.0f;
                #pragma unroll
                for (int nt = 0; nt < 4; ++nt) {
                    float e = __expf(sacc[nt][r] - m_run[r]);
                    sacc[nt][r] = e;
                    rs += e;
                }
                rs += __shfl_xor(rs, 1);
                rs += __shfl_xor(rs, 2);
                rs += __shfl_xor(rs, 4);
                rs += __shfl_xor(rs, 8);
                l_run[r] = l_run[r] * alpha[r] + rs;
            }
            #pragma unroll
            for (int o = 0; o < 8; ++o)
                #pragma unroll
                for (int r = 0; r < 4; ++r)
                    Oacc[o][r] *= alpha[r];

            // P (C/D layout) -> LDS (A-layout), wave-private
            #pragma unroll
            for (int nt = 0; nt < 4; ++nt)
                #pragma unroll
                for (int r = 0; r < 4; ++r)
                    sP[w][quad * 4 + r][nt * 16 + l16] = f2bf(sacc[nt][r]);

            bf16x8 pf[2];
            #pragma unroll
            for (int ks = 0; ks < 2; ++ks)
                pf[ks] = *(const bf16x8*)&sP[w][l16][ks * 32 + quad * 8];
            #pragma unroll
            for (int nt = 0; nt < 8; ++nt) {
                #pragma unroll
                for (int ks = 0; ks < 2; ++ks) {
                    int vr = nt * 16 + l16;
                    int p  = (ks * 4 + quad) ^ (vr & 7);
                    bf16x8 vf = *(const bf16x8*)&sVt[cur][vr][p * 8];
                    Oacc[nt] = __builtin_amdgcn_mfma_f32_16x16x32_bf16(pf[ks], vf, Oacc[nt], 0, 0, 0);
                }
            }
            cur ^= 1;
        }

        // finalize: O *= 1/l  (0 for empty rows and the zero_pad row q==0)
        float inv[4];
        #pragma unroll
        for (int r = 0; r < 4; ++r) {
            int m = q0 + w * 16 + quad * 4 + r;
            inv[r] = (l_run[r] > 0.0f && m != 0) ? 1.0f / l_run[r] : 0.0f;
        }
        #pragma unroll
        for (int nt = 0; nt < 8; ++nt)
            #pragma unroll
            for (int r = 0; r < 4; ++r) {
                int m = q0 + w * 16 + quad * 4 + r;
                Obuf[((size_t)b * S_ + m) * D_ + h * DK_ + nt * 16 + l16] =
                    f2bf(Oacc[nt][r] * inv[r]);
            }
    }
}

// ---------------------------------------------------------------- residual + LayerNorm
__global__ __launch_bounds__(256) void ln_res(
    const float* __restrict__ xin, const unsigned short* __restrict__ delta,
    const float* __restrict__ g, const float* __restrict__ bta,
    float* __restrict__ xout, unsigned short* __restrict__ xbout)
{
    __shared__ float red1[4], red2[4];
    const int row = blockIdx.x;
    const int tid = threadIdx.x;
    const int c = tid * 4;
    const float* xr = xin + (size_t)row * D_;
    const unsigned short* dr = delta + (size_t)row * D_;
    float4 xv = *(const float4*)(xr + c);
    ushort4 du = *(const ushort4*)(dr + c);
    float t0 = xv.x + bf2f(du.x), t1 = xv.y + bf2f(du.y);
    float t2 = xv.z + bf2f(du.z), t3 = xv.w + bf2f(du.w);

    float s = t0 + t1 + t2 + t3;
    #pragma unroll
    for (int off = 32; off > 0; off >>= 1) s += __shfl_down(s, off);
    if ((tid & 63) == 0) red1[tid >> 6] = s;
    __syncthreads();
    float mean = (red1[0] + red1[1] + red1[2] + red1[3]) * (1.0f / 1024.0f);

    float e0 = t0 - mean, e1 = t1 - mean, e2 = t2 - mean, e3 = t3 - mean;
    float ss = e0 * e0 + e1 * e1 + e2 * e2 + e3 * e3;
    #pragma unroll
    for (int off = 32; off > 0; off >>= 1) ss += __shfl_down(ss, off);
    if ((tid & 63) == 0) red2[tid >> 6] = ss;
    __syncthreads();
    float var = (red2[0] + red2[1] + red2[2] + red2[3]) * (1.0f / 1024.0f);
    float rstd = rsqrtf(var + 1e-5f);

    float4 gv = *(const float4*)(g + c);
    float4 bv = *(const float4*)(bta + c);
    float o0 = e0 * rstd * gv.x + bv.x;
    float o1 = e1 * rstd * gv.y + bv.y;
    float o2 = e2 * rstd * gv.z + bv.z;
    float o3 = e3 * rstd * gv.w + bv.w;
    *(float4*)(xout + (size_t)row * D_ + c) = make_float4(o0, o1, o2, o3);
    ushort4 ob; ob.x = f2bf(o0); ob.y = f2bf(o1); ob.z = f2bf(o2); ob.w = f2bf(o3);
    *(ushort4*)(xbout + (size_t)row * D_ + c) = ob;
}

// ---------------------------------------------------------------- driver
extern "C" void kernel_launch(void* const* d_in, const int* in_sizes, int n_in,
                              void* d_out, int out_size, void* d_ws, size_t ws_size,
                              hipStream_t stream)
{
    const float* qe   = (const float*)d_in[0];
    const float* qa   = (const float*)d_in[1];
    const float* pe   = (const float*)d_in[2];
    const float* Wk   = (const float*)d_in[3];
    const float* bk   = (const float*)d_in[4];
    const float* Wv   = (const float*)d_in[5];
    const float* bv   = (const float*)d_in[6];
    const float* Wo   = (const float*)d_in[7];
    const float* bo   = (const float*)d_in[8];
    const float* ln1g = (const float*)d_in[9];
    const float* ln1b = (const float*)d_in[10];
    const float* W1   = (const float*)d_in[11];
    const float* b1   = (const float*)d_in[12];
    const float* W2   = (const float*)d_in[13];
    const float* b2   = (const float*)d_in[14];
    const float* ln2g = (const float*)d_in[15];
    const float* ln2b = (const float*)d_in[16];

    const size_t BSD = (size_t)B_ * S_ * D_;
    const size_t BSF = (size_t)B_ * S_ * FF_;
    const size_t WDD = (size_t)D_ * D_;
    const size_t WFD = (size_t)FF_ * D_;

    char* p = (char*)d_ws;
    auto take = [&](size_t bytes) { char* r = p; p += (bytes + 255) & ~255ULL; return r; };
    float*          x32   = (float*)take(BSD * 4);
    unsigned short* xb    = (unsigned short*)take(BSD * 2);
    unsigned short* yb    = (unsigned short*)take(BSD * 2);
    unsigned short* delta = (unsigned short*)take(BSD * 2);
    char*           uni   = take(BSF * 2);
    unsigned short* Kb    = (unsigned short*)uni;
    unsigned short* Vt    = Kb + BSD;
    unsigned short* attnb = Vt + BSD;
    unsigned short* hb    = (unsigned short*)uni;
    unsigned short* wslot = (unsigned short*)take(WFD * 2);

    init_xy<<<(int)(BSD / 4 / 256), 256, 0, stream>>>(qe, qa, pe, x32, xb, yb);

    const int M = B_ * S_;
    for (int l = 0; l < L_; ++l) {
        cvt_bf16<<<(int)(WDD / 1024), 256, 0, stream>>>(Wk + l * WDD, wslot);
        gemm_bt<false, 1><<<dim3(D_ / 128, M / 128), 256, 0, stream>>>(
            xb, wslot, bk + l * D_, Kb, M, D_, D_);
        cvt_bf16<<<(int)(WDD / 1024), 256, 0, stream>>>(Wv + l * WDD, wslot);
        gemm_bt<false, 2><<<dim3(D_ / 128, M / 128), 256, 0, stream>>>(
            yb, wslot, bv + l * D_, Vt, M, D_, D_);
        attn_mfma<<<dim3(8, B_ * H_), 256, 0, stream>>>(Kb, Vt, attnb);
        cvt_bf16<<<(int)(WDD / 1024), 256, 0, stream>>>(Wo + l * WDD, wslot);
        gemm_bt<false, 1><<<dim3(D_ / 128, M / 128), 256, 0, stream>>>(
            attnb, wslot, bo + l * D_, delta, M, D_, D_);
        ln_res<<<M, 256, 0, stream>>>(x32, delta, ln1g + l * D_, ln1b + l * D_, x32, xb);
        cvt_bf16<<<(int)(WFD / 1024), 256, 0, stream>>>(W1 + l * WFD, wslot);
        gemm_bt<true, 1><<<dim3(FF_ / 128, M / 128), 256, 0, stream>>>(
            xb, wslot, b1 + l * FF_, hb, M, FF_, D_);
        cvt_bf16<<<(int)(WFD / 1024), 256, 0, stream>>>(W2 + l * WFD, wslot);
        gemm_bt<false, 1><<<dim3(D_ / 128, M / 128), 256, 0, stream>>>(
            hb, wslot, b2 + l * D_, delta, M, D_, FF_);
        float* xo = (l == L_ - 1) ? (float*)d_out : x32;
        ln_res<<<M, 256, 0, stream>>>(x32, delta, ln2g + l * D_, ln2b + l * D_, xo, xb);
    }
}

// Round 7
// 858.889 us; speedup vs baseline: 2.9376x; 1.0622x over previous
//
#include <hip/hip_runtime.h>
#include <hip/hip_bf16.h>
#include <cstdint>
#include <cstddef>

#define B_  8
#define S_  1024
#define D_  1024
#define H_  8
#define FF_ 4096
#define L_  2
#define DK_ 128

typedef __bf16 bf16x8 __attribute__((ext_vector_type(8)));
typedef float  f32x4  __attribute__((ext_vector_type(4)));

__device__ __forceinline__ unsigned short f2bf(float f) {
    union { float f; uint32_t u; } v; v.f = f;
    uint32_t r = v.u + 0x7fffu + ((v.u >> 16) & 1u);
    return (unsigned short)(r >> 16);
}
__device__ __forceinline__ float bf2f(unsigned short u) {
    union { uint32_t u; float f; } v; v.u = ((uint32_t)u) << 16; return v.f;
}

// ---------------------------------------------------------------- init: xb = qe+pe, yb = qa+pe (bf16)
__global__ __launch_bounds__(256) void init_xy(
    const float* __restrict__ qe, const float* __restrict__ qa,
    const float* __restrict__ pe,
    unsigned short* __restrict__ xb, unsigned short* __restrict__ yb)
{
    int i = (blockIdx.x * 256 + threadIdx.x) * 4;
    int pi = i & (S_ * D_ - 1);
    float4 q = *(const float4*)(qe + i);
    float4 a = *(const float4*)(qa + i);
    float4 p = *(const float4*)(pe + pi);
    ushort4 xo; xo.x = f2bf(q.x + p.x); xo.y = f2bf(q.y + p.y);
    xo.z = f2bf(q.z + p.z); xo.w = f2bf(q.w + p.w);
    ushort4 yo; yo.x = f2bf(a.x + p.x); yo.y = f2bf(a.y + p.y);
    yo.z = f2bf(a.z + p.z); yo.w = f2bf(a.w + p.w);
    *(ushort4*)(xb + i) = xo;
    *(ushort4*)(yb + i) = yo;
}

// ---------------------------------------------------------------- fp32 -> bf16 weight convert
__global__ __launch_bounds__(256) void cvt_bf16(
    const float* __restrict__ in, unsigned short* __restrict__ out)
{
    int i = (blockIdx.x * 256 + threadIdx.x) * 4;
    float4 f = *(const float4*)(in + i);
    ushort4 o; o.x = f2bf(f.x); o.y = f2bf(f.y); o.z = f2bf(f.z); o.w = f2bf(f.w);
    *(ushort4*)(out + i) = o;
}

// ---------------------------------------------------------------- dbuf m97-style bf16 MFMA NT-GEMM
// C[m,n] = sum_k A[m,k] * W[n,k] + bias[n]   (A: MxK bf16, W: NxK bf16)
// 128x128 tile, BK=64, 4 waves each 4x4 of 16x16x32 MFMA.
// Double-buffered global_load_lds (width 16): one barrier/iter, prefetch in flight
// during compute. XOR-chunk swizzle (chunk^row&7) for conflict-free ds_read_b128.
// OMODE: 1 = bf16 row-major out; 2 = bf16 per-head-transposed out [b,h][dim][key]
template<bool RELU, int OMODE>
__global__ __launch_bounds__(256) void gemm_bt(
    const unsigned short* __restrict__ A, const unsigned short* __restrict__ W,
    const float* __restrict__ bias, void* __restrict__ Cout,
    int M, int N, int K)
{
    __shared__ unsigned short sA[2][128][64];   // 2 x 16 KB
    __shared__ unsigned short sW[2][128][64];   // 2 x 16 KB

    const int tid  = threadIdx.x;
    const int lane = tid & 63;
    const int w    = tid >> 6;
    const int l16  = lane & 15;
    const int quad = lane >> 4;
    const int m0 = blockIdx.y * 128;
    const int n0 = blockIdx.x * 128;
    const int rw = (w >> 1) * 64;
    const int cw = (w & 1) * 64;

    const int srow   = lane >> 3;
    const int schunk = lane & 7;

    auto stage = [&](int k0, int buf) {
        #pragma unroll
        for (int i = 0; i < 4; ++i) {
            int r0  = w * 32 + i * 8;            // wave-uniform LDS row base
            int row = r0 + srow;
            int gc  = schunk ^ (row & 7);        // source-side swizzle
            const unsigned short* ga = A + (size_t)(m0 + row) * K + k0 + gc * 8;
            const unsigned short* gw = W + (size_t)(n0 + row) * K + k0 + gc * 8;
            __builtin_amdgcn_global_load_lds(
                (const __attribute__((address_space(1))) unsigned int*)ga,
                (__attribute__((address_space(3))) unsigned int*)&sA[buf][r0][0], 16, 0, 0);
            __builtin_amdgcn_global_load_lds(
                (const __attribute__((address_space(1))) unsigned int*)gw,
                (__attribute__((address_space(3))) unsigned int*)&sW[buf][r0][0], 16, 0, 0);
        }
    };

    f32x4 acc[4][4] = {};
    const int NK = K >> 6;
    int cur = 0;
    stage(0, 0);

    for (int kt = 0; kt < NK; ++kt) {
        __syncthreads();                         // drains tile-kt DMA; prev readers done
        if (kt + 1 < NK) stage((kt + 1) << 6, cur ^ 1);

        #pragma unroll
        for (int ks = 0; ks < 2; ++ks) {
            bf16x8 af[4], wf[4];
            #pragma unroll
            for (int t = 0; t < 4; ++t) {
                int arow = rw + t * 16 + l16;
                int achk = (ks * 4 + quad) ^ (arow & 7);
                af[t] = *(const bf16x8*)&sA[cur][arow][achk * 8];
                int wrow = cw + t * 16 + l16;
                int wchk = (ks * 4 + quad) ^ (wrow & 7);
                wf[t] = *(const bf16x8*)&sW[cur][wrow][wchk * 8];
            }
            #pragma unroll
            for (int it = 0; it < 4; ++it)
                #pragma unroll
                for (int jt = 0; jt < 4; ++jt)
                    acc[it][jt] = __builtin_amdgcn_mfma_f32_16x16x32_bf16(
                        af[it], wf[jt], acc[it][jt], 0, 0, 0);
        }
        cur ^= 1;
    }

    // epilogue: C/D layout col=lane&15, row=(lane>>4)*4+reg
    #pragma unroll
    for (int it = 0; it < 4; ++it)
        #pragma unroll
        for (int jt = 0; jt < 4; ++jt) {
            int row = m0 + rw + it * 16 + quad * 4;
            int col = n0 + cw + jt * 16 + l16;
            float bcol = bias[col];
            float v[4];
            #pragma unroll
            for (int r = 0; r < 4; ++r) {
                v[r] = acc[it][jt][r] + bcol;
                if (RELU) v[r] = fmaxf(v[r], 0.0f);
            }
            if (OMODE == 1) {
                #pragma unroll
                for (int r = 0; r < 4; ++r)
                    ((unsigned short*)Cout)[(size_t)(row + r) * N + col] = f2bf(v[r]);
            } else {
                int key = row & (S_ - 1);
                int bb  = row >> 10;
                int hh  = col >> 7, dim = col & (DK_ - 1);
                unsigned short* dst = (unsigned short*)Cout
                    + ((size_t)(bb * H_ + hh) * DK_ + dim) * S_ + key;
                ushort4 o4; o4.x = f2bf(v[0]); o4.y = f2bf(v[1]);
                o4.z = f2bf(v[2]); o4.w = f2bf(v[3]);
                *(ushort4*)dst = o4;
            }
        }
}

// ---------------------------------------------------------------- MFMA flash attention
// Q == K (kq_same). Strict causal (j < q). Row 0 output = 0 (zero_pad).
// Balanced pairing: block pa handles q-tiles {15-pa, pa} -> uniform 17 k-iters/block.
// Double-buffered global_load_lds staging; XOR-chunk swizzles for conflict-free reads.
__global__ __launch_bounds__(256) void attn_mfma(
    const unsigned short* __restrict__ Kbuf, const unsigned short* __restrict__ Vtbuf,
    unsigned short* __restrict__ Obuf)
{
    __shared__ unsigned short sK[2][64][128];
    __shared__ unsigned short sVt[2][128][64];
    __shared__ unsigned short sP[4][16][72];

    const int tid  = threadIdx.x;
    const int lane = tid & 63;
    const int w    = tid >> 6;
    const int l16  = lane & 15;
    const int quad = lane >> 4;
    const int pa   = blockIdx.x;
    const int bh   = blockIdx.y;
    const int b    = bh >> 3, h = bh & 7;
    const unsigned short* KB  = Kbuf  + ((size_t)b * S_) * D_ + h * DK_;
    const unsigned short* VTB = Vtbuf + (size_t)bh * DK_ * S_;

    const float scale = 0.08838834764831845f;

    auto stage = [&](int kt, int buf) {
        #pragma unroll
        for (int i = 0; i < 4; ++i) {
            int r0  = w * 16 + i * 4;
            int row = r0 + (lane >> 4);
            int c   = (lane & 15) ^ (row & 15);
            const unsigned short* g = KB + (size_t)(kt * 64 + row) * D_ + c * 8;
            __builtin_amdgcn_global_load_lds(
                (const __attribute__((address_space(1))) unsigned int*)g,
                (__attribute__((address_space(3))) unsigned int*)&sK[buf][r0][0], 16, 0, 0);
        }
        #pragma unroll
        for (int i = 0; i < 4; ++i) {
            int r0  = w * 32 + i * 8;
            int row = r0 + (lane >> 3);
            int c   = (lane & 7) ^ (row & 7);
            const unsigned short* g = VTB + (size_t)row * S_ + kt * 64 + c * 8;
            __builtin_amdgcn_global_load_lds(
                (const __attribute__((address_space(1))) unsigned int*)g,
                (__attribute__((address_space(3))) unsigned int*)&sVt[buf][r0][0], 16, 0, 0);
        }
    };

    #pragma unroll
    for (int half = 0; half < 2; ++half) {
        const int qt = half == 0 ? (15 - pa) : pa;
        const int q0 = qt * 64;

        bf16x8 qf[4];
        {
            const unsigned short* qrow = KB + (size_t)(q0 + w * 16 + l16) * D_ + quad * 8;
            #pragma unroll
            for (int ks = 0; ks < 4; ++ks)
                qf[ks] = *(const bf16x8*)(qrow + ks * 32);
        }

        f32x4 Oacc[8] = {};
        float m_run[4] = {-1e30f, -1e30f, -1e30f, -1e30f};
        float l_run[4] = {};

        int cur = 0;
        stage(0, cur);

        for (int kt = 0; kt <= qt; ++kt) {
            __syncthreads();
            if (kt < qt) stage(kt + 1, cur ^ 1);

            f32x4 sacc[4];
            #pragma unroll
            for (int nt = 0; nt < 4; ++nt) {
                f32x4 a = {};
                #pragma unroll
                for (int ks = 0; ks < 4; ++ks) {
                    int kr = nt * 16 + l16;
                    int p  = (ks * 4 + quad) ^ (kr & 15);
                    bf16x8 kf = *(const bf16x8*)&sK[cur][kr][p * 8];
                    a = __builtin_amdgcn_mfma_f32_16x16x32_bf16(qf[ks], kf, a, 0, 0, 0);
                }
                sacc[nt] = a;
            }

            const bool diag = (kt == qt);
            #pragma unroll
            for (int nt = 0; nt < 4; ++nt)
                #pragma unroll
                for (int r = 0; r < 4; ++r) {
                    float v = sacc[nt][r] * scale;
                    if (diag) {
                        int nidx = nt * 16 + l16;
                        int midx = w * 16 + quad * 4 + r;
                        if (nidx >= midx) v = -1e30f;
                    }
                    sacc[nt][r] = v;
                }

            float alpha[4];
            #pragma unroll
            for (int r = 0; r < 4; ++r) {
                float mx = fmaxf(fmaxf(sacc[0][r], sacc[1][r]), fmaxf(sacc[2][r], sacc[3][r]));
                mx = fmaxf(mx, __shfl_xor(mx, 1));
                mx = fmaxf(mx, __shfl_xor(mx, 2));
                mx = fmaxf(mx, __shfl_xor(mx, 4));
                mx = fmaxf(mx, __shfl_xor(mx, 8));
                float mn = fmaxf(m_run[r], mx);
                alpha[r] = __expf(m_run[r] - mn);
                m_run[r] = mn;
            }
            #pragma unroll
            for (int r = 0; r < 4; ++r) {
                float rs = 0.0f;
                #pragma unroll
                for (int nt = 0; nt < 4; ++nt) {
                    float e = __expf(sacc[nt][r] - m_run[r]);
                    sacc[nt][r] = e;
                    rs += e;
                }
                rs += __shfl_xor(rs, 1);
                rs += __shfl_xor(rs, 2);
                rs += __shfl_xor(rs, 4);
                rs += __shfl_xor(rs, 8);
                l_run[r] = l_run[r] * alpha[r] + rs;
            }
            #pragma unroll
            for (int o = 0; o < 8; ++o)
                #pragma unroll
                for (int r = 0; r < 4; ++r)
                    Oacc[o][r] *= alpha[r];

            #pragma unroll
            for (int nt = 0; nt < 4; ++nt)
                #pragma unroll
                for (int r = 0; r < 4; ++r)
                    sP[w][quad * 4 + r][nt * 16 + l16] = f2bf(sacc[nt][r]);

            bf16x8 pf[2];
            #pragma unroll
            for (int ks = 0; ks < 2; ++ks)
                pf[ks] = *(const bf16x8*)&sP[w][l16][ks * 32 + quad * 8];
            #pragma unroll
            for (int nt = 0; nt < 8; ++nt) {
                #pragma unroll
                for (int ks = 0; ks < 2; ++ks) {
                    int vr = nt * 16 + l16;
                    int p  = (ks * 4 + quad) ^ (vr & 7);
                    bf16x8 vf = *(const bf16x8*)&sVt[cur][vr][p * 8];
                    Oacc[nt] = __builtin_amdgcn_mfma_f32_16x16x32_bf16(pf[ks], vf, Oacc[nt], 0, 0, 0);
                }
            }
            cur ^= 1;
        }

        float inv[4];
        #pragma unroll
        for (int r = 0; r < 4; ++r) {
            int m = q0 + w * 16 + quad * 4 + r;
            inv[r] = (l_run[r] > 0.0f && m != 0) ? 1.0f / l_run[r] : 0.0f;
        }
        #pragma unroll
        for (int nt = 0; nt < 8; ++nt)
            #pragma unroll
            for (int r = 0; r < 4; ++r) {
                int m = q0 + w * 16 + quad * 4 + r;
                Obuf[((size_t)b * S_ + m) * D_ + h * DK_ + nt * 16 + l16] =
                    f2bf(Oacc[nt][r] * inv[r]);
            }
    }
}

// ---------------------------------------------------------------- residual + LayerNorm (bf16 residual)
// t = xb + delta; out = LN(t)*g + b. FINAL: write fp32 to fout; else write bf16 xb in place.
template<bool FINAL>
__global__ __launch_bounds__(256) void ln_res(
    const unsigned short* __restrict__ xin, const unsigned short* __restrict__ delta,
    const float* __restrict__ g, const float* __restrict__ bta,
    unsigned short* __restrict__ xbout, float* __restrict__ fout)
{
    __shared__ float red1[4], red2[4];
    const int row = blockIdx.x;
    const int tid = threadIdx.x;
    const int c = tid * 4;
    ushort4 xu = *(const ushort4*)(xin + (size_t)row * D_ + c);
    ushort4 du = *(const ushort4*)(delta + (size_t)row * D_ + c);
    float t0 = bf2f(xu.x) + bf2f(du.x), t1 = bf2f(xu.y) + bf2f(du.y);
    float t2 = bf2f(xu.z) + bf2f(du.z), t3 = bf2f(xu.w) + bf2f(du.w);

    float s = t0 + t1 + t2 + t3;
    #pragma unroll
    for (int off = 32; off > 0; off >>= 1) s += __shfl_down(s, off);
    if ((tid & 63) == 0) red1[tid >> 6] = s;
    __syncthreads();
    float mean = (red1[0] + red1[1] + red1[2] + red1[3]) * (1.0f / 1024.0f);

    float e0 = t0 - mean, e1 = t1 - mean, e2 = t2 - mean, e3 = t3 - mean;
    float ss = e0 * e0 + e1 * e1 + e2 * e2 + e3 * e3;
    #pragma unroll
    for (int off = 32; off > 0; off >>= 1) ss += __shfl_down(ss, off);
    if ((tid & 63) == 0) red2[tid >> 6] = ss;
    __syncthreads();
    float var = (red2[0] + red2[1] + red2[2] + red2[3]) * (1.0f / 1024.0f);
    float rstd = rsqrtf(var + 1e-5f);

    float4 gv = *(const float4*)(g + c);
    float4 bv = *(const float4*)(bta + c);
    float o0 = e0 * rstd * gv.x + bv.x;
    float o1 = e1 * rstd * gv.y + bv.y;
    float o2 = e2 * rstd * gv.z + bv.z;
    float o3 = e3 * rstd * gv.w + bv.w;
    if (FINAL) {
        *(float4*)(fout + (size_t)row * D_ + c) = make_float4(o0, o1, o2, o3);
    } else {
        ushort4 ob; ob.x = f2bf(o0); ob.y = f2bf(o1); ob.z = f2bf(o2); ob.w = f2bf(o3);
        *(ushort4*)(xbout + (size_t)row * D_ + c) = ob;
    }
}

// ---------------------------------------------------------------- driver
extern "C" void kernel_launch(void* const* d_in, const int* in_sizes, int n_in,
                              void* d_out, int out_size, void* d_ws, size_t ws_size,
                              hipStream_t stream)
{
    const float* qe   = (const float*)d_in[0];
    const float* qa   = (const float*)d_in[1];
    const float* pe   = (const float*)d_in[2];
    const float* Wk   = (const float*)d_in[3];
    const float* bk   = (const float*)d_in[4];
    const float* Wv   = (const float*)d_in[5];
    const float* bv   = (const float*)d_in[6];
    const float* Wo   = (const float*)d_in[7];
    const float* bo   = (const float*)d_in[8];
    const float* ln1g = (const float*)d_in[9];
    const float* ln1b = (const float*)d_in[10];
    const float* W1   = (const float*)d_in[11];
    const float* b1   = (const float*)d_in[12];
    const float* W2   = (const float*)d_in[13];
    const float* b2   = (const float*)d_in[14];
    const float* ln2g = (const float*)d_in[15];
    const float* ln2b = (const float*)d_in[16];

    const size_t BSD = (size_t)B_ * S_ * D_;
    const size_t BSF = (size_t)B_ * S_ * FF_;
    const size_t WDD = (size_t)D_ * D_;
    const size_t WFD = (size_t)FF_ * D_;

    // ws layout (~126 MB): xb 16.8 | yb 16.8 | delta 16.8 |
    //   union 67.1 {Kb,Vt,attnb | hb} | wslot 8.4
    char* p = (char*)d_ws;
    auto take = [&](size_t bytes) { char* r = p; p += (bytes + 255) & ~255ULL; return r; };
    unsigned short* xb    = (unsigned short*)take(BSD * 2);
    unsigned short* yb    = (unsigned short*)take(BSD * 2);
    unsigned short* delta = (unsigned short*)take(BSD * 2);
    char*           uni   = take(BSF * 2);
    unsigned short* Kb    = (unsigned short*)uni;
    unsigned short* Vt    = Kb + BSD;
    unsigned short* attnb = Vt + BSD;
    unsigned short* hb    = (unsigned short*)uni;
    unsigned short* wslot = (unsigned short*)take(WFD * 2);

    init_xy<<<(int)(BSD / 4 / 256), 256, 0, stream>>>(qe, qa, pe, xb, yb);

    const int M = B_ * S_;
    for (int l = 0; l < L_; ++l) {
        cvt_bf16<<<(int)(WDD / 1024), 256, 0, stream>>>(Wk + l * WDD, wslot);
        gemm_bt<false, 1><<<dim3(D_ / 128, M / 128), 256, 0, stream>>>(
            xb, wslot, bk + l * D_, Kb, M, D_, D_);
        cvt_bf16<<<(int)(WDD / 1024), 256, 0, stream>>>(Wv + l * WDD, wslot);
        gemm_bt<false, 2><<<dim3(D_ / 128, M / 128), 256, 0, stream>>>(
            yb, wslot, bv + l * D_, Vt, M, D_, D_);
        attn_mfma<<<dim3(8, B_ * H_), 256, 0, stream>>>(Kb, Vt, attnb);
        cvt_bf16<<<(int)(WDD / 1024), 256, 0, stream>>>(Wo + l * WDD, wslot);
        gemm_bt<false, 1><<<dim3(D_ / 128, M / 128), 256, 0, stream>>>(
            attnb, wslot, bo + l * D_, delta, M, D_, D_);
        ln_res<false><<<M, 256, 0, stream>>>(xb, delta, ln1g + l * D_, ln1b + l * D_, xb, nullptr);
        cvt_bf16<<<(int)(WFD / 1024), 256, 0, stream>>>(W1 + l * WFD, wslot);
        gemm_bt<true, 1><<<dim3(FF_ / 128, M / 128), 256, 0, stream>>>(
            xb, wslot, b1 + l * FF_, hb, M, FF_, D_);
        cvt_bf16<<<(int)(WFD / 1024), 256, 0, stream>>>(W2 + l * WFD, wslot);
        gemm_bt<false, 1><<<dim3(D_ / 128, M / 128), 256, 0, stream>>>(
            hb, wslot, b2 + l * D_, delta, M, D_, FF_);
        if (l == L_ - 1)
            ln_res<true><<<M, 256, 0, stream>>>(xb, delta, ln2g + l * D_, ln2b + l * D_,
                                               nullptr, (float*)d_out);
        else
            ln_res<false><<<M, 256, 0, stream>>>(xb, delta, ln2g + l * D_, ln2b + l * D_,
                                                xb, nullptr);
    }
}